// Round 11
// baseline (462.902 us; speedup 1.0000x reference)
//
#include <hip/hip_runtime.h>

typedef float f32x4 __attribute__((ext_vector_type(4)));
typedef short bf16x8 __attribute__((ext_vector_type(8)));

__device__ __forceinline__ unsigned short bf16r(float f) {
  unsigned int u = __float_as_uint(f);
  return (unsigned short)((u + 0x7FFFu + ((u >> 16) & 1u)) >> 16);
}
__device__ __forceinline__ float bf2f(unsigned short h) {
  return __uint_as_float((unsigned int)h << 16);
}

// ================= CSR build =================
__global__ __launch_bounds__(256) void hist_kernel(const int* __restrict__ dst,
                                                   int* __restrict__ deg, int E) {
  int e = blockIdx.x * 256 + threadIdx.x;
  if (e < E) atomicAdd(&deg[dst[e]], 1);
}

__global__ __launch_bounds__(1024) void scan_kernel(const int* __restrict__ deg,
                                                    int* __restrict__ rowstart,
                                                    int* __restrict__ cursor, int N) {
  __shared__ int sums[1024];
  const int t = threadIdx.x;
  const int CH = (N + 1023) >> 10;
  int local[32];
  int base = t * CH;
  int s = 0;
  for (int i = 0; i < CH; i++) {
    int idx = base + i;
    int v = (idx < N) ? deg[idx] : 0;
    local[i] = s;
    s += v;
  }
  sums[t] = s;
  __syncthreads();
  for (int off = 1; off < 1024; off <<= 1) {
    int add = (t >= off) ? sums[t - off] : 0;
    __syncthreads();
    sums[t] += add;
    __syncthreads();
  }
  int prefix = sums[t] - s;
  for (int i = 0; i < CH; i++) {
    int idx = base + i;
    if (idx < N) {
      int v = prefix + local[i];
      rowstart[idx] = v;
      cursor[idx] = v;
    }
  }
  if (t == 1023) rowstart[N] = sums[1023];
}

__global__ __launch_bounds__(256) void fill_kernel(const int* __restrict__ src,
                                                   const int* __restrict__ dst,
                                                   int* __restrict__ cursor,
                                                   int* __restrict__ nbr, int E) {
  int e = blockIdx.x * 256 + threadIdx.x;
  if (e >= E) return;
  int pos = atomicAdd(&cursor[dst[e]], 1);
  nbr[pos] = src[e];
}

// ============ gather aggregation, optional fused BN(scale/shift)+ReLU on inputs ============
template <int C, bool BNIN>
__global__ __launch_bounds__(256) void gather_agg_kernel(
    const float* __restrict__ x, const int* __restrict__ rowstart,
    const int* __restrict__ nbr, const float* __restrict__ stats,
    float* __restrict__ agg, int N) {
  constexpr int Din = 64 * C;
  const int wave = threadIdx.x >> 6;
  const int lane = threadIdx.x & 63;
  const int node = blockIdx.x * 4 + wave;
  if (node >= N) return;

  float sc[C], sh[C];
  if constexpr (BNIN) {
#pragma unroll
    for (int j = 0; j < C; j++) {
      sc[j] = stats[lane * C + j];
      sh[j] = stats[Din + lane * C + j];
    }
  }

  float acc[C];
  {
    const float* p = x + (size_t)node * Din + lane * C;
    float v[C];
    if constexpr (C == 2) {
      float2 t = *(const float2*)p; v[0] = t.x; v[1] = t.y;
    } else {
      float4 t = *(const float4*)p; v[0] = t.x; v[1] = t.y; v[2] = t.z; v[3] = t.w;
    }
#pragma unroll
    for (int j = 0; j < C; j++)
      acc[j] = BNIN ? fmaxf(v[j] * sc[j] + sh[j], 0.f) : v[j];
  }
  const int rs = rowstart[node], re = rowstart[node + 1];
  for (int e = rs; e < re; e++) {
    int s0 = nbr[e];
    const float* p = x + (size_t)s0 * Din + lane * C;
    float v[C];
    if constexpr (C == 2) {
      float2 t = *(const float2*)p; v[0] = t.x; v[1] = t.y;
    } else {
      float4 t = *(const float4*)p; v[0] = t.x; v[1] = t.y; v[2] = t.z; v[3] = t.w;
    }
#pragma unroll
    for (int j = 0; j < C; j++)
      acc[j] += BNIN ? fmaxf(v[j] * sc[j] + sh[j], 0.f) : v[j];
  }
  float* o = agg + (size_t)node * Din + lane * C;
  if constexpr (C == 2) {
    *(float2*)o = make_float2(acc[0], acc[1]);
  } else {
    *(float4*)o = make_float4(acc[0], acc[1], acc[2], acc[3]);
  }
}

// ================= weight prep: W[K][N] fp32 -> WT_hi/lo [N][K] bf16 =================
__global__ __launch_bounds__(256) void wprep_kernel(const float* __restrict__ W,
                                                    unsigned short* __restrict__ TH,
                                                    unsigned short* __restrict__ TL,
                                                    int K, int N) {
  int idx = blockIdx.x * 256 + threadIdx.x;
  if (idx >= K * N) return;
  int k = idx / N, n = idx - k * N;
  float v = W[idx];
  unsigned short h = bf16r(v);
  TH[(size_t)n * K + k] = h;
  TL[(size_t)n * K + k] = bf16r(v - bf2f(h));
}

// ===== MFMA GEMM: C = A[MxK] @ B[KxN] + bias, split-bf16 (truncated-hi), inline conversion ==
// RT rows x (64*CF) cols per block, 4 waves (wave = 16*CF cols x RT rows), BK=64.
// Conflict-free LDS staging: thread tid writes slot (tid&63) -> linear 16B/lane.
// XCD swizzle: all col-blocks of a row panel land on one XCD.
template <int RT, int CF>
__global__ __launch_bounds__(256) void gemm_mfma_kernel(
    const float* __restrict__ A, const unsigned short* __restrict__ BT_hi,
    const unsigned short* __restrict__ BT_lo, const float* __restrict__ bias,
    float* __restrict__ C, int M, int K, int N, int mblocks, int cbShift,
    int doRelu, float* __restrict__ stats) {
  constexpr int NF = RT / 16;       // row frags per 32-K half
  constexpr int NP = RT / 32;       // staging passes per thread
  __shared__ unsigned short Ah[2 * NF * 512];
  __shared__ unsigned short Al[2 * NF * 512];
  const int bid = blockIdx.x;
  const int xcd = bid & 7;
  const int q = bid >> 3;
  const int r = ((q >> cbShift) << 3) + xcd;
  const int cb = q & ((1 << cbShift) - 1);
  if (r >= mblocks) return;

  const int tid = threadIdx.x;
  const int lane = tid & 63;
  const int w = tid >> 6;
  const int rowBase = r * RT;
  const int colBase = cb * (64 * CF) + w * (16 * CF);

  f32x4 acc[NF][CF] = {};

  const int c0 = colBase + (lane & 15);
  const int kfrag = (lane >> 4) * 8;

  // conflict-free staging map: slot = tid&63 within frag
  const int row16 = tid & 15;
  const int kg = (tid >> 4) & 3;
  int srow, fragBase;
  if constexpr (RT == 64) {
    const int rt = tid >> 6;
    srow = (rt << 4) | row16;
    fragBase = rt;               // frag = i*NF + rt, kk = kg*8 + i*32
  } else {                       // RT == 32, single pass
    const int half = (tid >> 6) & 1;
    const int rt = tid >> 7;
    srow = (rt << 4) | row16;
    fragBase = half * NF + rt;   // kk = kg*8 + half*32
  }
  const int kkHalf = (RT == 32) ? ((tid >> 6) & 1) * 32 : 0;
  const size_t arowOff = (size_t)(rowBase + srow) * K;
  const bool srowOk = (rowBase + srow) < M;
  const int slot8 = (tid & 63) * 8;

  for (int k0 = 0; k0 < K; k0 += 64) {
#pragma unroll
    for (int i = 0; i < NP; i++) {
      int kk = k0 + kg * 8 + (RT == 64 ? i * 32 : kkHalf);
      float v[8];
      if (srowOk) {
        float4 a = *(const float4*)(A + arowOff + kk);
        float4 b = *(const float4*)(A + arowOff + kk + 4);
        v[0] = a.x; v[1] = a.y; v[2] = a.z; v[3] = a.w;
        v[4] = b.x; v[5] = b.y; v[6] = b.z; v[7] = b.w;
      } else {
#pragma unroll
        for (int j = 0; j < 8; j++) v[j] = 0.f;
      }
      bf16x8 h8, l8;
#pragma unroll
      for (int j = 0; j < 8; j++) {
        unsigned int u = __float_as_uint(v[j]);
        unsigned short h = (unsigned short)(u >> 16);  // truncated hi; lo corrects it
        h8[j] = (short)h;
        float rsd = v[j] - bf2f(h);
        l8[j] = (short)(unsigned short)(__float_as_uint(rsd) >> 16);
      }
      int frag = (RT == 64 ? i * NF + fragBase : fragBase);
      *(bf16x8*)(Ah + frag * 512 + slot8) = h8;
      *(bf16x8*)(Al + frag * 512 + slot8) = l8;
    }
    __syncthreads();
#pragma unroll
    for (int ks = 0; ks < 2; ks++) {
      int kidx = k0 + ks * 32 + kfrag;
      bf16x8 bh[CF], bl[CF];
#pragma unroll
      for (int cf = 0; cf < CF; cf++) {
        bh[cf] = *(const bf16x8*)(BT_hi + (size_t)(c0 + cf * 16) * K + kidx);
        bl[cf] = *(const bf16x8*)(BT_lo + (size_t)(c0 + cf * 16) * K + kidx);
      }
#pragma unroll
      for (int fi = 0; fi < NF; fi++) {
        int frag = ks * NF + fi;
        bf16x8 ah = *(const bf16x8*)(Ah + frag * 512 + lane * 8);
        bf16x8 al = *(const bf16x8*)(Al + frag * 512 + lane * 8);
#pragma unroll
        for (int cf = 0; cf < CF; cf++) {
          acc[fi][cf] = __builtin_amdgcn_mfma_f32_16x16x32_bf16(ah, bh[cf], acc[fi][cf], 0, 0, 0);
          acc[fi][cf] = __builtin_amdgcn_mfma_f32_16x16x32_bf16(al, bh[cf], acc[fi][cf], 0, 0, 0);
          acc[fi][cf] = __builtin_amdgcn_mfma_f32_16x16x32_bf16(ah, bl[cf], acc[fi][cf], 0, 0, 0);
        }
      }
    }
    __syncthreads();
  }

  // epilogue
  float bs[CF];
#pragma unroll
  for (int cf = 0; cf < CF; cf++) bs[cf] = bias[c0 + cf * 16];
  float s1[CF], s2[CF];
#pragma unroll
  for (int cf = 0; cf < CF; cf++) { s1[cf] = 0.f; s2[cf] = 0.f; }
  const int rbase = rowBase + (lane >> 4) * 4;
#pragma unroll
  for (int fi = 0; fi < NF; fi++) {
#pragma unroll
    for (int j = 0; j < 4; j++) {
      int row = rbase + fi * 16 + j;
      if (row < M) {
#pragma unroll
        for (int cf = 0; cf < CF; cf++) {
          float v = acc[fi][cf][j] + bs[cf];
          if (doRelu) v = fmaxf(v, 0.f);
          C[(size_t)row * N + c0 + cf * 16] = v;
          s1[cf] += v;
          s2[cf] += v * v;
        }
      }
    }
  }
  if (stats) {
#pragma unroll
    for (int cf = 0; cf < CF; cf++) {
#pragma unroll
      for (int off = 16; off < 64; off <<= 1) {
        s1[cf] += __shfl_xor(s1[cf], off);
        s2[cf] += __shfl_xor(s2[cf], off);
      }
    }
    if ((lane >> 4) == 0) {
#pragma unroll
      for (int cf = 0; cf < CF; cf++) {
        atomicAdd(&stats[c0 + cf * 16], s1[cf]);
        atomicAdd(&stats[N + c0 + cf * 16], s2[cf]);
      }
    }
  }
}

// ================= BN fold =================
__global__ __launch_bounds__(256) void bn_prep_kernel(float* __restrict__ stats,
                                                      const float* __restrict__ gamma,
                                                      const float* __restrict__ beta,
                                                      int D, float invN) {
  int c = blockIdx.x * 256 + threadIdx.x;
  if (c >= D) return;
  float mean = stats[c] * invN;
  float var = stats[D + c] * invN - mean * mean;
  float sc = rsqrtf(var + 1e-5f) * gamma[c];
  stats[c] = sc;
  stats[D + c] = beta[c] - mean * sc;
}

// ============ fused BN+ReLU+segment-mean pool (layer 3, D=512) ============
__global__ __launch_bounds__(256) void bn_pool_kernel(
    const float* __restrict__ h, const float* __restrict__ stats,
    const int* __restrict__ batch, float* __restrict__ pooled, int N) {
  const int g = blockIdx.x >> 3;
  const int s = blockIdx.x & 7;
  __shared__ int s_lo, s_hi;
  if (threadIdx.x == 0) {
    int lo = 0, hi = N;
    while (lo < hi) { int m = (lo + hi) >> 1; if (batch[m] < g) lo = m + 1; else hi = m; }
    s_lo = lo;
    lo = 0; hi = N;
    while (lo < hi) { int m = (lo + hi) >> 1; if (batch[m] < g + 1) lo = m + 1; else hi = m; }
    s_hi = lo;
  }
  __syncthreads();
  const int lo = s_lo, hi = s_hi, len = hi - lo;
  if (len == 0) return;
  const int per = (len + 7) >> 3;
  const int rs = lo + s * per;
  const int re = min(rs + per, hi);
  if (rs >= re) return;
  const int t = threadIdx.x;
  float2 sc = *(const float2*)(stats + 2 * t);
  float2 sh = *(const float2*)(stats + 512 + 2 * t);
  float ax = 0.f, ay = 0.f;
  for (int r = rs; r < re; r++) {
    float2 v = *(const float2*)(h + (size_t)r * 512 + 2 * t);
    ax += fmaxf(v.x * sc.x + sh.x, 0.f);
    ay += fmaxf(v.y * sc.y + sh.y, 0.f);
  }
  float inv = 1.f / (float)len;
  atomicAdd(&pooled[g * 512 + 2 * t], ax * inv);
  atomicAdd(&pooled[g * 512 + 2 * t + 1], ay * inv);
}

// ================= final projection =================
__global__ __launch_bounds__(64) void out_kernel(const float* __restrict__ pooled,
                                                 const float* __restrict__ wo,
                                                 const float* __restrict__ bo,
                                                 float* __restrict__ out) {
  int g = blockIdx.x, o = threadIdx.x;
  float acc = bo[o];
  for (int c = 0; c < 512; c++) acc += pooled[g * 512 + c] * wo[c * 64 + o];
  out[g * 64 + o] = fmaxf(acc, 0.f);
}

extern "C" void kernel_launch(void* const* d_in, const int* in_sizes, int n_in,
                              void* d_out, int out_size, void* d_ws, size_t ws_size,
                              hipStream_t stream) {
  const float* x0 = (const float*)d_in[0];
  const int* ei = (const int*)d_in[1];
  const int* batch = (const int*)d_in[2];
  const int N = in_sizes[0] / 128;
  const int E = in_sizes[1] / 2;
  const int* src = ei;
  const int* dst = ei + E;
  const float* W[3][6];
  for (int li = 0; li < 3; li++)
    for (int k = 0; k < 6; k++) W[li][k] = (const float*)d_in[3 + li * 6 + k];
  const float* wo = (const float*)d_in[21];
  const float* bo = (const float*)d_in[22];
  float* out = (float*)d_out;

  // workspace layout
  float* agg = (float*)d_ws;                 // N*256
  float* h1 = agg + (size_t)N * 256;         // N*512
  float* h2 = h1 + (size_t)N * 512;          // N*512
  float* stats = h2 + (size_t)N * 512;       // 1024
  float* pooled = stats + 1024;              // 64*512
  int* deg = (int*)(pooled + 64 * 512);      // N
  int* rowstart = deg + N;                   // N+1
  int* cursor = rowstart + N + 1;            // N
  int* nbr = cursor + N;                     // E
  uintptr_t wp = (uintptr_t)(nbr + E);
  wp = (wp + 15) & ~(uintptr_t)15;
  unsigned short* wbuf = (unsigned short*)wp;

  const int dins[3] = {128, 128, 256};
  const int douts[3] = {128, 256, 512};

  unsigned short* WT[3][4];
  {
    unsigned short* p = wbuf;
    for (int li = 0; li < 3; li++) {
      size_t s1 = (size_t)dins[li] * douts[li];
      size_t s2 = (size_t)douts[li] * douts[li];
      WT[li][0] = p; p += s1;
      WT[li][1] = p; p += s1;
      WT[li][2] = p; p += s2;
      WT[li][3] = p; p += s2;
    }
  }
  for (int li = 0; li < 3; li++) {
    int e1 = dins[li] * douts[li];
    int e2 = douts[li] * douts[li];
    wprep_kernel<<<(e1 + 255) / 256, 256, 0, stream>>>(W[li][0], WT[li][0], WT[li][1], dins[li], douts[li]);
    wprep_kernel<<<(e2 + 255) / 256, 256, 0, stream>>>(W[li][2], WT[li][2], WT[li][3], douts[li], douts[li]);
  }

  // CSR build
  hipMemsetAsync(deg, 0, (size_t)N * sizeof(int), stream);
  hist_kernel<<<(E + 255) / 256, 256, 0, stream>>>(dst, deg, E);
  scan_kernel<<<1, 1024, 0, stream>>>(deg, rowstart, cursor, N);
  fill_kernel<<<(E + 255) / 256, 256, 0, stream>>>(src, dst, cursor, nbr, E);

  const int mb64 = (N + 63) / 64;
  const int mb64_8 = ((mb64 + 7) / 8) * 8;
  const int mb32 = (N + 31) / 32;
  const int mb32_8 = ((mb32 + 7) / 8) * 8;
  const int gblocks = (N + 3) / 4;

  for (int li = 0; li < 3; li++) {
    int Din = dins[li], Dout = douts[li];
    if (li == 0)
      gather_agg_kernel<2, false><<<gblocks, 256, 0, stream>>>(x0, rowstart, nbr, nullptr, agg, N);
    else if (li == 1)
      gather_agg_kernel<2, true><<<gblocks, 256, 0, stream>>>(h2, rowstart, nbr, stats, agg, N);
    else
      gather_agg_kernel<4, true><<<gblocks, 256, 0, stream>>>(h2, rowstart, nbr, stats, agg, N);

    if (Dout == 128) {
      // RT=32, CF=2 -> block covers 32 x 128
      int nblocks = mb32_8;
      gemm_mfma_kernel<32, 2><<<nblocks, 256, 0, stream>>>(agg, WT[li][0], WT[li][1], W[li][1], h1,
                                                           N, Din, Dout, mb32, 0, 1, nullptr);
      hipMemsetAsync(stats, 0, 2 * Dout * sizeof(float), stream);
      gemm_mfma_kernel<32, 2><<<nblocks, 256, 0, stream>>>(h1, WT[li][2], WT[li][3], W[li][3], h2,
                                                           N, Dout, Dout, mb32, 0, 0, stats);
    } else {
      // RT=64, CF=4 -> block covers 64 x 256
      int cbShift = (Dout == 256) ? 0 : 1;
      int nblocks = mb64_8 << cbShift;
      gemm_mfma_kernel<64, 4><<<nblocks, 256, 0, stream>>>(agg, WT[li][0], WT[li][1], W[li][1], h1,
                                                           N, Din, Dout, mb64, cbShift, 1, nullptr);
      hipMemsetAsync(stats, 0, 2 * Dout * sizeof(float), stream);
      gemm_mfma_kernel<64, 4><<<nblocks, 256, 0, stream>>>(h1, WT[li][2], WT[li][3], W[li][3], h2,
                                                           N, Dout, Dout, mb64, cbShift, 0, stats);
    }
    bn_prep_kernel<<<(Dout + 255) / 256, 256, 0, stream>>>(stats, W[li][4], W[li][5], Dout, 1.0f / N);
    if (li == 2) {
      hipMemsetAsync(pooled, 0, 64 * 512 * sizeof(float), stream);
      bn_pool_kernel<<<64 * 8, 256, 0, stream>>>(h2, stats, batch, pooled, N);
    }
  }
  out_kernel<<<64, 64, 0, stream>>>(pooled, wo, bo, out);
}

// Round 12
// 443.141 us; speedup vs baseline: 1.0446x; 1.0446x over previous
//
#include <hip/hip_runtime.h>

typedef float f32x4 __attribute__((ext_vector_type(4)));
typedef short bf16x8 __attribute__((ext_vector_type(8)));

__device__ __forceinline__ unsigned short bf16r(float f) {
  unsigned int u = __float_as_uint(f);
  return (unsigned short)((u + 0x7FFFu + ((u >> 16) & 1u)) >> 16);
}
__device__ __forceinline__ float bf2f(unsigned short h) {
  return __uint_as_float((unsigned int)h << 16);
}

// ================= CSR build =================
__global__ __launch_bounds__(256) void hist_kernel(const int* __restrict__ dst,
                                                   int* __restrict__ deg, int E) {
  int e = blockIdx.x * 256 + threadIdx.x;
  if (e < E) atomicAdd(&deg[dst[e]], 1);
}

__global__ __launch_bounds__(1024) void scan_kernel(const int* __restrict__ deg,
                                                    int* __restrict__ rowstart,
                                                    int* __restrict__ cursor, int N) {
  __shared__ int sums[1024];
  const int t = threadIdx.x;
  const int CH = (N + 1023) >> 10;
  int local[32];
  int base = t * CH;
  int s = 0;
  for (int i = 0; i < CH; i++) {
    int idx = base + i;
    int v = (idx < N) ? deg[idx] : 0;
    local[i] = s;
    s += v;
  }
  sums[t] = s;
  __syncthreads();
  for (int off = 1; off < 1024; off <<= 1) {
    int add = (t >= off) ? sums[t - off] : 0;
    __syncthreads();
    sums[t] += add;
    __syncthreads();
  }
  int prefix = sums[t] - s;
  for (int i = 0; i < CH; i++) {
    int idx = base + i;
    if (idx < N) {
      int v = prefix + local[i];
      rowstart[idx] = v;
      cursor[idx] = v;
    }
  }
  if (t == 1023) rowstart[N] = sums[1023];
}

__global__ __launch_bounds__(256) void fill_kernel(const int* __restrict__ src,
                                                   const int* __restrict__ dst,
                                                   int* __restrict__ cursor,
                                                   int* __restrict__ nbr, int E) {
  int e = blockIdx.x * 256 + threadIdx.x;
  if (e >= E) return;
  int pos = atomicAdd(&cursor[dst[e]], 1);
  nbr[pos] = src[e];
}

// ============ gather aggregation, optional fused BN(scale/shift)+ReLU on inputs ============
template <int C, bool BNIN>
__global__ __launch_bounds__(256) void gather_agg_kernel(
    const float* __restrict__ x, const int* __restrict__ rowstart,
    const int* __restrict__ nbr, const float* __restrict__ stats,
    float* __restrict__ agg, int N) {
  constexpr int Din = 64 * C;
  const int wave = threadIdx.x >> 6;
  const int lane = threadIdx.x & 63;
  const int node = blockIdx.x * 4 + wave;
  if (node >= N) return;

  float sc[C], sh[C];
  if constexpr (BNIN) {
#pragma unroll
    for (int j = 0; j < C; j++) {
      sc[j] = stats[lane * C + j];
      sh[j] = stats[Din + lane * C + j];
    }
  }

  float acc[C];
  {
    const float* p = x + (size_t)node * Din + lane * C;
    float v[C];
    if constexpr (C == 2) {
      float2 t = *(const float2*)p; v[0] = t.x; v[1] = t.y;
    } else {
      float4 t = *(const float4*)p; v[0] = t.x; v[1] = t.y; v[2] = t.z; v[3] = t.w;
    }
#pragma unroll
    for (int j = 0; j < C; j++)
      acc[j] = BNIN ? fmaxf(v[j] * sc[j] + sh[j], 0.f) : v[j];
  }
  const int rs = rowstart[node], re = rowstart[node + 1];
  for (int e = rs; e < re; e++) {
    int s0 = nbr[e];
    const float* p = x + (size_t)s0 * Din + lane * C;
    float v[C];
    if constexpr (C == 2) {
      float2 t = *(const float2*)p; v[0] = t.x; v[1] = t.y;
    } else {
      float4 t = *(const float4*)p; v[0] = t.x; v[1] = t.y; v[2] = t.z; v[3] = t.w;
    }
#pragma unroll
    for (int j = 0; j < C; j++)
      acc[j] += BNIN ? fmaxf(v[j] * sc[j] + sh[j], 0.f) : v[j];
  }
  float* o = agg + (size_t)node * Din + lane * C;
  if constexpr (C == 2) {
    *(float2*)o = make_float2(acc[0], acc[1]);
  } else {
    *(float4*)o = make_float4(acc[0], acc[1], acc[2], acc[3]);
  }
}

// ================= weight prep: W[K][N] fp32 -> WT_hi/lo [N][K] bf16 =================
__global__ __launch_bounds__(256) void wprep_kernel(const float* __restrict__ W,
                                                    unsigned short* __restrict__ TH,
                                                    unsigned short* __restrict__ TL,
                                                    int K, int N) {
  int idx = blockIdx.x * 256 + threadIdx.x;
  if (idx >= K * N) return;
  int k = idx / N, n = idx - k * N;
  float v = W[idx];
  unsigned short h = bf16r(v);
  TH[(size_t)n * K + k] = h;
  TL[(size_t)n * K + k] = bf16r(v - bf2f(h));
}

// ===== MFMA GEMM: C = A[MxK] @ B[KxN] + bias, split-bf16 (truncated-hi), inline conversion ==
// RT rows x 128 cols per block, 4 waves (wave = 32 cols x RT rows), BK=64.
// Conflict-free LDS staging: thread tid writes slot (tid&63) within its fragment.
// XCD swizzle: all col-blocks of a row panel land on one XCD.
template <int RT>
__global__ __launch_bounds__(256) void gemm_mfma_kernel(
    const float* __restrict__ A, const unsigned short* __restrict__ BT_hi,
    const unsigned short* __restrict__ BT_lo, const float* __restrict__ bias,
    float* __restrict__ C, int M, int K, int N, int mblocks, int cbShift,
    int doRelu, float* __restrict__ stats) {
  constexpr int NF = RT / 16;       // row frags per 32-K half
  constexpr int NP = RT / 32;       // staging passes per thread
  __shared__ unsigned short Ah[2 * NF * 512];
  __shared__ unsigned short Al[2 * NF * 512];
  const int bid = blockIdx.x;
  const int xcd = bid & 7;
  const int q = bid >> 3;
  const int r = ((q >> cbShift) << 3) + xcd;
  const int cb = q & ((1 << cbShift) - 1);
  if (r >= mblocks) return;

  const int tid = threadIdx.x;
  const int lane = tid & 63;
  const int w = tid >> 6;
  const int rowBase = r * RT;
  const int colBase = cb * 128 + w * 32;

  f32x4 acc[NF][2] = {};

  const int c0 = colBase + (lane & 15);
  const int kfrag = (lane >> 4) * 8;

  // conflict-free staging map: thread (row16, kg) writes slot (tid&63), linear 16B/lane
  const int row16 = tid & 15;
  const int kg = (tid >> 4) & 3;
  int srow, fragBase, kkHalf;
  if constexpr (RT == 64) {
    const int rt = tid >> 6;
    srow = (rt << 4) | row16;
    fragBase = rt;               // frag = i*NF + rt, kk = kg*8 + i*32
    kkHalf = 0;
  } else {                       // RT == 32, single pass
    const int half = (tid >> 6) & 1;
    const int rt = tid >> 7;
    srow = (rt << 4) | row16;
    fragBase = half * NF + rt;
    kkHalf = half * 32;          // kk = kg*8 + half*32
  }
  const size_t arowOff = (size_t)(rowBase + srow) * K;
  const bool srowOk = (rowBase + srow) < M;
  const int slot8 = (tid & 63) * 8;

  for (int k0 = 0; k0 < K; k0 += 64) {
#pragma unroll
    for (int i = 0; i < NP; i++) {
      int kk = k0 + kg * 8 + (RT == 64 ? i * 32 : kkHalf);
      float v[8];
      if (srowOk) {
        float4 a = *(const float4*)(A + arowOff + kk);
        float4 b = *(const float4*)(A + arowOff + kk + 4);
        v[0] = a.x; v[1] = a.y; v[2] = a.z; v[3] = a.w;
        v[4] = b.x; v[5] = b.y; v[6] = b.z; v[7] = b.w;
      } else {
#pragma unroll
        for (int j = 0; j < 8; j++) v[j] = 0.f;
      }
      bf16x8 h8, l8;
#pragma unroll
      for (int j = 0; j < 8; j++) {
        unsigned int u = __float_as_uint(v[j]);
        unsigned short h = (unsigned short)(u >> 16);  // truncated hi; lo corrects it
        h8[j] = (short)h;
        float rsd = v[j] - bf2f(h);
        l8[j] = (short)(unsigned short)(__float_as_uint(rsd) >> 16);
      }
      int frag = (RT == 64 ? i * NF + fragBase : fragBase);
      *(bf16x8*)(Ah + frag * 512 + slot8) = h8;
      *(bf16x8*)(Al + frag * 512 + slot8) = l8;
    }
    __syncthreads();
#pragma unroll
    for (int ks = 0; ks < 2; ks++) {
      int kidx = k0 + ks * 32 + kfrag;
      bf16x8 bh0 = *(const bf16x8*)(BT_hi + (size_t)c0 * K + kidx);
      bf16x8 bl0 = *(const bf16x8*)(BT_lo + (size_t)c0 * K + kidx);
      bf16x8 bh1 = *(const bf16x8*)(BT_hi + (size_t)(c0 + 16) * K + kidx);
      bf16x8 bl1 = *(const bf16x8*)(BT_lo + (size_t)(c0 + 16) * K + kidx);
#pragma unroll
      for (int fi = 0; fi < NF; fi++) {
        int frag = ks * NF + fi;
        bf16x8 ah = *(const bf16x8*)(Ah + frag * 512 + lane * 8);
        bf16x8 al = *(const bf16x8*)(Al + frag * 512 + lane * 8);
        acc[fi][0] = __builtin_amdgcn_mfma_f32_16x16x32_bf16(ah, bh0, acc[fi][0], 0, 0, 0);
        acc[fi][0] = __builtin_amdgcn_mfma_f32_16x16x32_bf16(al, bh0, acc[fi][0], 0, 0, 0);
        acc[fi][0] = __builtin_amdgcn_mfma_f32_16x16x32_bf16(ah, bl0, acc[fi][0], 0, 0, 0);
        acc[fi][1] = __builtin_amdgcn_mfma_f32_16x16x32_bf16(ah, bh1, acc[fi][1], 0, 0, 0);
        acc[fi][1] = __builtin_amdgcn_mfma_f32_16x16x32_bf16(al, bh1, acc[fi][1], 0, 0, 0);
        acc[fi][1] = __builtin_amdgcn_mfma_f32_16x16x32_bf16(ah, bl1, acc[fi][1], 0, 0, 0);
      }
    }
    __syncthreads();
  }

  // epilogue
  const float bias0 = bias[c0], bias1 = bias[c0 + 16];
  float s1[2] = {0.f, 0.f}, s2[2] = {0.f, 0.f};
  const int rbase = rowBase + (lane >> 4) * 4;
#pragma unroll
  for (int fi = 0; fi < NF; fi++) {
#pragma unroll
    for (int j = 0; j < 4; j++) {
      int row = rbase + fi * 16 + j;
      float v0 = acc[fi][0][j] + bias0;
      float v1 = acc[fi][1][j] + bias1;
      if (doRelu) { v0 = fmaxf(v0, 0.f); v1 = fmaxf(v1, 0.f); }
      if (row < M) {
        C[(size_t)row * N + c0] = v0;
        C[(size_t)row * N + c0 + 16] = v1;
        s1[0] += v0; s2[0] += v0 * v0;
        s1[1] += v1; s2[1] += v1 * v1;
      }
    }
  }
  if (stats) {
#pragma unroll
    for (int off = 16; off < 64; off <<= 1) {
      s1[0] += __shfl_xor(s1[0], off);
      s2[0] += __shfl_xor(s2[0], off);
      s1[1] += __shfl_xor(s1[1], off);
      s2[1] += __shfl_xor(s2[1], off);
    }
    if (lane < 16) {
      atomicAdd(&stats[c0], s1[0]);
      atomicAdd(&stats[N + c0], s2[0]);
      atomicAdd(&stats[c0 + 16], s1[1]);
      atomicAdd(&stats[N + c0 + 16], s2[1]);
    }
  }
}

// ================= BN fold =================
__global__ __launch_bounds__(256) void bn_prep_kernel(float* __restrict__ stats,
                                                      const float* __restrict__ gamma,
                                                      const float* __restrict__ beta,
                                                      int D, float invN) {
  int c = blockIdx.x * 256 + threadIdx.x;
  if (c >= D) return;
  float mean = stats[c] * invN;
  float var = stats[D + c] * invN - mean * mean;
  float sc = rsqrtf(var + 1e-5f) * gamma[c];
  stats[c] = sc;
  stats[D + c] = beta[c] - mean * sc;
}

// ============ fused BN+ReLU+segment-mean pool (layer 3, D=512) ============
__global__ __launch_bounds__(256) void bn_pool_kernel(
    const float* __restrict__ h, const float* __restrict__ stats,
    const int* __restrict__ batch, float* __restrict__ pooled, int N) {
  const int g = blockIdx.x >> 3;
  const int s = blockIdx.x & 7;
  __shared__ int s_lo, s_hi;
  if (threadIdx.x == 0) {
    int lo = 0, hi = N;
    while (lo < hi) { int m = (lo + hi) >> 1; if (batch[m] < g) lo = m + 1; else hi = m; }
    s_lo = lo;
    lo = 0; hi = N;
    while (lo < hi) { int m = (lo + hi) >> 1; if (batch[m] < g + 1) lo = m + 1; else hi = m; }
    s_hi = lo;
  }
  __syncthreads();
  const int lo = s_lo, hi = s_hi, len = hi - lo;
  if (len == 0) return;
  const int per = (len + 7) >> 3;
  const int rs = lo + s * per;
  const int re = min(rs + per, hi);
  if (rs >= re) return;
  const int t = threadIdx.x;
  float2 sc = *(const float2*)(stats + 2 * t);
  float2 sh = *(const float2*)(stats + 512 + 2 * t);
  float ax = 0.f, ay = 0.f;
  for (int r = rs; r < re; r++) {
    float2 v = *(const float2*)(h + (size_t)r * 512 + 2 * t);
    ax += fmaxf(v.x * sc.x + sh.x, 0.f);
    ay += fmaxf(v.y * sc.y + sh.y, 0.f);
  }
  float inv = 1.f / (float)len;
  atomicAdd(&pooled[g * 512 + 2 * t], ax * inv);
  atomicAdd(&pooled[g * 512 + 2 * t + 1], ay * inv);
}

// ================= final projection =================
__global__ __launch_bounds__(64) void out_kernel(const float* __restrict__ pooled,
                                                 const float* __restrict__ wo,
                                                 const float* __restrict__ bo,
                                                 float* __restrict__ out) {
  int g = blockIdx.x, o = threadIdx.x;
  float acc = bo[o];
  for (int c = 0; c < 512; c++) acc += pooled[g * 512 + c] * wo[c * 64 + o];
  out[g * 64 + o] = fmaxf(acc, 0.f);
}

extern "C" void kernel_launch(void* const* d_in, const int* in_sizes, int n_in,
                              void* d_out, int out_size, void* d_ws, size_t ws_size,
                              hipStream_t stream) {
  const float* x0 = (const float*)d_in[0];
  const int* ei = (const int*)d_in[1];
  const int* batch = (const int*)d_in[2];
  const int N = in_sizes[0] / 128;
  const int E = in_sizes[1] / 2;
  const int* src = ei;
  const int* dst = ei + E;
  const float* W[3][6];
  for (int li = 0; li < 3; li++)
    for (int k = 0; k < 6; k++) W[li][k] = (const float*)d_in[3 + li * 6 + k];
  const float* wo = (const float*)d_in[21];
  const float* bo = (const float*)d_in[22];
  float* out = (float*)d_out;

  // workspace layout
  float* agg = (float*)d_ws;                 // N*256
  float* h1 = agg + (size_t)N * 256;         // N*512
  float* h2 = h1 + (size_t)N * 512;          // N*512
  float* stats = h2 + (size_t)N * 512;       // 1024
  float* pooled = stats + 1024;              // 64*512
  int* deg = (int*)(pooled + 64 * 512);      // N
  int* rowstart = deg + N;                   // N+1
  int* cursor = rowstart + N + 1;            // N
  int* nbr = cursor + N;                     // E
  uintptr_t wp = (uintptr_t)(nbr + E);
  wp = (wp + 15) & ~(uintptr_t)15;
  unsigned short* wbuf = (unsigned short*)wp;

  const int dins[3] = {128, 128, 256};
  const int douts[3] = {128, 256, 512};

  unsigned short* WT[3][4];
  {
    unsigned short* p = wbuf;
    for (int li = 0; li < 3; li++) {
      size_t s1 = (size_t)dins[li] * douts[li];
      size_t s2 = (size_t)douts[li] * douts[li];
      WT[li][0] = p; p += s1;
      WT[li][1] = p; p += s1;
      WT[li][2] = p; p += s2;
      WT[li][3] = p; p += s2;
    }
  }
  for (int li = 0; li < 3; li++) {
    int e1 = dins[li] * douts[li];
    int e2 = douts[li] * douts[li];
    wprep_kernel<<<(e1 + 255) / 256, 256, 0, stream>>>(W[li][0], WT[li][0], WT[li][1], dins[li], douts[li]);
    wprep_kernel<<<(e2 + 255) / 256, 256, 0, stream>>>(W[li][2], WT[li][2], WT[li][3], douts[li], douts[li]);
  }

  // CSR build
  hipMemsetAsync(deg, 0, (size_t)N * sizeof(int), stream);
  hist_kernel<<<(E + 255) / 256, 256, 0, stream>>>(dst, deg, E);
  scan_kernel<<<1, 1024, 0, stream>>>(deg, rowstart, cursor, N);
  fill_kernel<<<(E + 255) / 256, 256, 0, stream>>>(src, dst, cursor, nbr, E);

  const int mb64 = (N + 63) / 64;
  const int mb64_8 = ((mb64 + 7) / 8) * 8;
  const int mb32 = (N + 31) / 32;
  const int mb32_8 = ((mb32 + 7) / 8) * 8;
  const int gblocks = (N + 3) / 4;

  for (int li = 0; li < 3; li++) {
    int Din = dins[li], Dout = douts[li];
    if (li == 0)
      gather_agg_kernel<2, false><<<gblocks, 256, 0, stream>>>(x0, rowstart, nbr, nullptr, agg, N);
    else if (li == 1)
      gather_agg_kernel<2, true><<<gblocks, 256, 0, stream>>>(h2, rowstart, nbr, stats, agg, N);
    else
      gather_agg_kernel<4, true><<<gblocks, 256, 0, stream>>>(h2, rowstart, nbr, stats, agg, N);

    if (Dout == 128) {
      int nblocks = mb32_8;
      gemm_mfma_kernel<32><<<nblocks, 256, 0, stream>>>(agg, WT[li][0], WT[li][1], W[li][1], h1,
                                                        N, Din, Dout, mb32, 0, 1, nullptr);
      hipMemsetAsync(stats, 0, 2 * Dout * sizeof(float), stream);
      gemm_mfma_kernel<32><<<nblocks, 256, 0, stream>>>(h1, WT[li][2], WT[li][3], W[li][3], h2,
                                                        N, Dout, Dout, mb32, 0, 0, stats);
    } else {
      int cbShift = (Dout == 256) ? 1 : 2;
      int nblocks = mb64_8 << cbShift;
      gemm_mfma_kernel<64><<<nblocks, 256, 0, stream>>>(agg, WT[li][0], WT[li][1], W[li][1], h1,
                                                        N, Din, Dout, mb64, cbShift, 1, nullptr);
      hipMemsetAsync(stats, 0, 2 * Dout * sizeof(float), stream);
      gemm_mfma_kernel<64><<<nblocks, 256, 0, stream>>>(h1, WT[li][2], WT[li][3], W[li][3], h2,
                                                        N, Dout, Dout, mb64, cbShift, 0, stats);
    }
    bn_prep_kernel<<<(Dout + 255) / 256, 256, 0, stream>>>(stats, W[li][4], W[li][5], Dout, 1.0f / N);
    if (li == 2) {
      hipMemsetAsync(pooled, 0, 64 * 512 * sizeof(float), stream);
      bn_pool_kernel<<<64 * 8, 256, 0, stream>>>(h2, stats, batch, pooled, N);
    }
  }
  out_kernel<<<64, 64, 0, stream>>>(pooled, wo, bo, out);
}

// Round 13
// 439.609 us; speedup vs baseline: 1.0530x; 1.0080x over previous
//
#include <hip/hip_runtime.h>

typedef float f32x4 __attribute__((ext_vector_type(4)));
typedef short bf16x8 __attribute__((ext_vector_type(8)));

__device__ __forceinline__ unsigned short bf16r(float f) {
  unsigned int u = __float_as_uint(f);
  return (unsigned short)((u + 0x7FFFu + ((u >> 16) & 1u)) >> 16);
}
__device__ __forceinline__ float bf2f(unsigned short h) {
  return __uint_as_float((unsigned int)h << 16);
}

// ================= CSR build =================
__global__ __launch_bounds__(256) void hist_kernel(const int* __restrict__ dst,
                                                   int* __restrict__ deg, int E) {
  int e = blockIdx.x * 256 + threadIdx.x;
  if (e < E) atomicAdd(&deg[dst[e]], 1);
}

__global__ __launch_bounds__(1024) void scan_kernel(const int* __restrict__ deg,
                                                    int* __restrict__ rowstart,
                                                    int* __restrict__ cursor, int N) {
  __shared__ int sums[1024];
  const int t = threadIdx.x;
  const int CH = (N + 1023) >> 10;
  int local[32];
  int base = t * CH;
  int s = 0;
  for (int i = 0; i < CH; i++) {
    int idx = base + i;
    int v = (idx < N) ? deg[idx] : 0;
    local[i] = s;
    s += v;
  }
  sums[t] = s;
  __syncthreads();
  for (int off = 1; off < 1024; off <<= 1) {
    int add = (t >= off) ? sums[t - off] : 0;
    __syncthreads();
    sums[t] += add;
    __syncthreads();
  }
  int prefix = sums[t] - s;
  for (int i = 0; i < CH; i++) {
    int idx = base + i;
    if (idx < N) {
      int v = prefix + local[i];
      rowstart[idx] = v;
      cursor[idx] = v;
    }
  }
  if (t == 1023) rowstart[N] = sums[1023];
}

__global__ __launch_bounds__(256) void fill_kernel(const int* __restrict__ src,
                                                   const int* __restrict__ dst,
                                                   int* __restrict__ cursor,
                                                   int* __restrict__ nbr, int E) {
  int e = blockIdx.x * 256 + threadIdx.x;
  if (e >= E) return;
  int pos = atomicAdd(&cursor[dst[e]], 1);
  nbr[pos] = src[e];
}

// ============ gather aggregation, optional fused BN(scale/shift)+ReLU on inputs ============
template <int C, bool BNIN>
__global__ __launch_bounds__(256) void gather_agg_kernel(
    const float* __restrict__ x, const int* __restrict__ rowstart,
    const int* __restrict__ nbr, const float* __restrict__ stats,
    float* __restrict__ agg, int N) {
  constexpr int Din = 64 * C;
  const int wave = threadIdx.x >> 6;
  const int lane = threadIdx.x & 63;
  const int node = blockIdx.x * 4 + wave;
  if (node >= N) return;

  float sc[C], sh[C];
  if constexpr (BNIN) {
#pragma unroll
    for (int j = 0; j < C; j++) {
      sc[j] = stats[lane * C + j];
      sh[j] = stats[Din + lane * C + j];
    }
  }

  float acc[C];
  {
    const float* p = x + (size_t)node * Din + lane * C;
    float v[C];
    if constexpr (C == 2) {
      float2 t = *(const float2*)p; v[0] = t.x; v[1] = t.y;
    } else {
      float4 t = *(const float4*)p; v[0] = t.x; v[1] = t.y; v[2] = t.z; v[3] = t.w;
    }
#pragma unroll
    for (int j = 0; j < C; j++)
      acc[j] = BNIN ? fmaxf(v[j] * sc[j] + sh[j], 0.f) : v[j];
  }
  const int rs = rowstart[node], re = rowstart[node + 1];
  for (int e = rs; e < re; e++) {
    int s0 = nbr[e];
    const float* p = x + (size_t)s0 * Din + lane * C;
    float v[C];
    if constexpr (C == 2) {
      float2 t = *(const float2*)p; v[0] = t.x; v[1] = t.y;
    } else {
      float4 t = *(const float4*)p; v[0] = t.x; v[1] = t.y; v[2] = t.z; v[3] = t.w;
    }
#pragma unroll
    for (int j = 0; j < C; j++)
      acc[j] += BNIN ? fmaxf(v[j] * sc[j] + sh[j], 0.f) : v[j];
  }
  float* o = agg + (size_t)node * Din + lane * C;
  if constexpr (C == 2) {
    *(float2*)o = make_float2(acc[0], acc[1]);
  } else {
    *(float4*)o = make_float4(acc[0], acc[1], acc[2], acc[3]);
  }
}

// ================= batched weight prep: 6 matrices in one launch =================
struct WSeg {
  const float* W;
  unsigned short* TH;
  unsigned short* TL;
  int K, N, total;
};
struct WAll { WSeg s[6]; };

__global__ __launch_bounds__(256) void wprep_all_kernel(WAll a) {
  WSeg sg = a.s[blockIdx.y];
  int idx = blockIdx.x * 256 + threadIdx.x;
  if (idx >= sg.total) return;
  int k = idx / sg.N, n = idx - k * sg.N;
  float v = sg.W[idx];
  unsigned short h = bf16r(v);
  sg.TH[(size_t)n * sg.K + k] = h;
  sg.TL[(size_t)n * sg.K + k] = bf16r(v - bf2f(h));
}

// ===== MFMA GEMM: C = A[MxK] @ B[KxN] + bias, split-bf16, inline round-hi/lo conversion =====
// RT rows x (NW*32) cols per block, NW waves; wave = 32 cols x RT rows; BK=64.
// NW=8: wave w stages fragment w entirely (linear conflict-free LDS writes).
// NW=4 (RT=32): r10 single-pass map. XCD swizzle keeps a row panel on one XCD.
template <int RT, int NW>
__global__ __launch_bounds__(NW * 64) void gemm_mfma_kernel(
    const float* __restrict__ A, const unsigned short* __restrict__ BT_hi,
    const unsigned short* __restrict__ BT_lo, const float* __restrict__ bias,
    float* __restrict__ C, int M, int K, int N, int mblocks, int cbShift,
    int doRelu, float* __restrict__ stats) {
  constexpr int NF = RT / 16;  // row frags per 32-K half
  __shared__ unsigned short Ah[2 * NF * 512];
  __shared__ unsigned short Al[2 * NF * 512];
  const int bid = blockIdx.x;
  const int xcd = bid & 7;
  const int q = bid >> 3;
  const int r = ((q >> cbShift) << 3) + xcd;
  const int cb = q & ((1 << cbShift) - 1);
  if (r >= mblocks) return;

  const int tid = threadIdx.x;
  const int lane = tid & 63;
  const int w = tid >> 6;
  const int rowBase = r * RT;
  const int colBase = cb * (NW * 32) + w * 32;

  f32x4 acc[NF][2] = {};
  const int c0 = colBase + (lane & 15);
  const int kfrag = (lane >> 4) * 8;

  // single-pass staging maps
  int srow, kk0, sfrag, slot8;
  if constexpr (NW == 8) {
    // wave w owns fragment w: rows (w&3)*16 + (lane&15), k-half (w>>2), k-chunk (lane>>4)
    srow = (w & 3) * 16 + (lane & 15);
    kk0 = (w >> 2) * 32 + (lane >> 4) * 8;
    sfrag = w;
    slot8 = lane * 8;  // linear 16B/lane -> conflict-free
  } else {
    // r10 RT=32 map
    srow = tid >> 3;
    const int c8 = tid & 7;
    const int lc = c8 & 3, ks = c8 >> 2;
    kk0 = lc * 8 + ks * 32;
    sfrag = ks * NF + (srow >> 4);
    slot8 = ((srow & 15) | (lc << 4)) * 8;
  }
  const size_t arowOff = (size_t)(rowBase + srow) * K;
  const bool srowOk = (rowBase + srow) < M;

  for (int k0 = 0; k0 < K; k0 += 64) {
    {
      int kk = k0 + kk0;
      float v[8];
      if (srowOk) {
        float4 a = *(const float4*)(A + arowOff + kk);
        float4 b = *(const float4*)(A + arowOff + kk + 4);
        v[0] = a.x; v[1] = a.y; v[2] = a.z; v[3] = a.w;
        v[4] = b.x; v[5] = b.y; v[6] = b.z; v[7] = b.w;
      } else {
#pragma unroll
        for (int j = 0; j < 8; j++) v[j] = 0.f;
      }
      bf16x8 h8, l8;
#pragma unroll
      for (int j = 0; j < 8; j++) {
        unsigned short h = bf16r(v[j]);
        h8[j] = (short)h;
        l8[j] = (short)bf16r(v[j] - bf2f(h));
      }
      *(bf16x8*)(Ah + sfrag * 512 + slot8) = h8;
      *(bf16x8*)(Al + sfrag * 512 + slot8) = l8;
    }
    __syncthreads();
#pragma unroll
    for (int ks = 0; ks < 2; ks++) {
      int kidx = k0 + ks * 32 + kfrag;
      bf16x8 bh0 = *(const bf16x8*)(BT_hi + (size_t)c0 * K + kidx);
      bf16x8 bl0 = *(const bf16x8*)(BT_lo + (size_t)c0 * K + kidx);
      bf16x8 bh1 = *(const bf16x8*)(BT_hi + (size_t)(c0 + 16) * K + kidx);
      bf16x8 bl1 = *(const bf16x8*)(BT_lo + (size_t)(c0 + 16) * K + kidx);
#pragma unroll
      for (int fi = 0; fi < NF; fi++) {
        int frag = ks * NF + fi;
        bf16x8 ah = *(const bf16x8*)(Ah + frag * 512 + lane * 8);
        bf16x8 al = *(const bf16x8*)(Al + frag * 512 + lane * 8);
        acc[fi][0] = __builtin_amdgcn_mfma_f32_16x16x32_bf16(ah, bh0, acc[fi][0], 0, 0, 0);
        acc[fi][0] = __builtin_amdgcn_mfma_f32_16x16x32_bf16(al, bh0, acc[fi][0], 0, 0, 0);
        acc[fi][0] = __builtin_amdgcn_mfma_f32_16x16x32_bf16(ah, bl0, acc[fi][0], 0, 0, 0);
        acc[fi][1] = __builtin_amdgcn_mfma_f32_16x16x32_bf16(ah, bh1, acc[fi][1], 0, 0, 0);
        acc[fi][1] = __builtin_amdgcn_mfma_f32_16x16x32_bf16(al, bh1, acc[fi][1], 0, 0, 0);
        acc[fi][1] = __builtin_amdgcn_mfma_f32_16x16x32_bf16(ah, bl1, acc[fi][1], 0, 0, 0);
      }
    }
    __syncthreads();
  }

  // epilogue
  const float bias0 = bias[c0], bias1 = bias[c0 + 16];
  float s1[2] = {0.f, 0.f}, s2[2] = {0.f, 0.f};
  const int rbase = rowBase + (lane >> 4) * 4;
#pragma unroll
  for (int fi = 0; fi < NF; fi++) {
#pragma unroll
    for (int j = 0; j < 4; j++) {
      int row = rbase + fi * 16 + j;
      float v0 = acc[fi][0][j] + bias0;
      float v1 = acc[fi][1][j] + bias1;
      if (doRelu) { v0 = fmaxf(v0, 0.f); v1 = fmaxf(v1, 0.f); }
      if (row < M) {
        C[(size_t)row * N + c0] = v0;
        C[(size_t)row * N + c0 + 16] = v1;
        s1[0] += v0; s2[0] += v0 * v0;
        s1[1] += v1; s2[1] += v1 * v1;
      }
    }
  }
  if (stats) {
#pragma unroll
    for (int off = 16; off < 64; off <<= 1) {
      s1[0] += __shfl_xor(s1[0], off);
      s2[0] += __shfl_xor(s2[0], off);
      s1[1] += __shfl_xor(s1[1], off);
      s2[1] += __shfl_xor(s2[1], off);
    }
    if (lane < 16) {
      atomicAdd(&stats[c0], s1[0]);
      atomicAdd(&stats[N + c0], s2[0]);
      atomicAdd(&stats[c0 + 16], s1[1]);
      atomicAdd(&stats[N + c0 + 16], s2[1]);
    }
  }
}

// ================= BN fold =================
__global__ __launch_bounds__(256) void bn_prep_kernel(float* __restrict__ stats,
                                                      const float* __restrict__ gamma,
                                                      const float* __restrict__ beta,
                                                      int D, float invN) {
  int c = blockIdx.x * 256 + threadIdx.x;
  if (c >= D) return;
  float mean = stats[c] * invN;
  float var = stats[D + c] * invN - mean * mean;
  float sc = rsqrtf(var + 1e-5f) * gamma[c];
  stats[c] = sc;
  stats[D + c] = beta[c] - mean * sc;
}

// ============ fused BN+ReLU+segment-mean pool (layer 3, D=512) ============
__global__ __launch_bounds__(256) void bn_pool_kernel(
    const float* __restrict__ h, const float* __restrict__ stats,
    const int* __restrict__ batch, float* __restrict__ pooled, int N) {
  const int g = blockIdx.x >> 3;
  const int s = blockIdx.x & 7;
  __shared__ int s_lo, s_hi;
  if (threadIdx.x == 0) {
    int lo = 0, hi = N;
    while (lo < hi) { int m = (lo + hi) >> 1; if (batch[m] < g) lo = m + 1; else hi = m; }
    s_lo = lo;
    lo = 0; hi = N;
    while (lo < hi) { int m = (lo + hi) >> 1; if (batch[m] < g + 1) lo = m + 1; else hi = m; }
    s_hi = lo;
  }
  __syncthreads();
  const int lo = s_lo, hi = s_hi, len = hi - lo;
  if (len == 0) return;
  const int per = (len + 7) >> 3;
  const int rs = lo + s * per;
  const int re = min(rs + per, hi);
  if (rs >= re) return;
  const int t = threadIdx.x;
  float2 sc = *(const float2*)(stats + 2 * t);
  float2 sh = *(const float2*)(stats + 512 + 2 * t);
  float ax = 0.f, ay = 0.f;
  for (int r = rs; r < re; r++) {
    float2 v = *(const float2*)(h + (size_t)r * 512 + 2 * t);
    ax += fmaxf(v.x * sc.x + sh.x, 0.f);
    ay += fmaxf(v.y * sc.y + sh.y, 0.f);
  }
  float inv = 1.f / (float)len;
  atomicAdd(&pooled[g * 512 + 2 * t], ax * inv);
  atomicAdd(&pooled[g * 512 + 2 * t + 1], ay * inv);
}

// ================= final projection =================
__global__ __launch_bounds__(64) void out_kernel(const float* __restrict__ pooled,
                                                 const float* __restrict__ wo,
                                                 const float* __restrict__ bo,
                                                 float* __restrict__ out) {
  int g = blockIdx.x, o = threadIdx.x;
  float acc = bo[o];
  for (int c = 0; c < 512; c++) acc += pooled[g * 512 + c] * wo[c * 64 + o];
  out[g * 64 + o] = fmaxf(acc, 0.f);
}

extern "C" void kernel_launch(void* const* d_in, const int* in_sizes, int n_in,
                              void* d_out, int out_size, void* d_ws, size_t ws_size,
                              hipStream_t stream) {
  const float* x0 = (const float*)d_in[0];
  const int* ei = (const int*)d_in[1];
  const int* batch = (const int*)d_in[2];
  const int N = in_sizes[0] / 128;
  const int E = in_sizes[1] / 2;
  const int* src = ei;
  const int* dst = ei + E;
  const float* W[3][6];
  for (int li = 0; li < 3; li++)
    for (int k = 0; k < 6; k++) W[li][k] = (const float*)d_in[3 + li * 6 + k];
  const float* wo = (const float*)d_in[21];
  const float* bo = (const float*)d_in[22];
  float* out = (float*)d_out;

  // workspace layout
  float* agg = (float*)d_ws;                 // N*256
  float* h1 = agg + (size_t)N * 256;         // N*512
  float* h2 = h1 + (size_t)N * 512;          // N*512
  float* stats3 = h2 + (size_t)N * 512;      // 3*1024 (per-layer stats regions)
  float* pooled = stats3 + 3 * 1024;         // 64*512 (adjacent -> one memset)
  int* deg = (int*)(pooled + 64 * 512);      // N
  int* rowstart = deg + N;                   // N+1
  int* cursor = rowstart + N + 1;            // N
  int* nbr = cursor + N;                     // E
  uintptr_t wp = (uintptr_t)(nbr + E);
  wp = (wp + 15) & ~(uintptr_t)15;
  unsigned short* wbuf = (unsigned short*)wp;

  const int dins[3] = {128, 128, 256};
  const int douts[3] = {128, 256, 512};

  unsigned short* WT[3][4];
  {
    unsigned short* p = wbuf;
    for (int li = 0; li < 3; li++) {
      size_t s1 = (size_t)dins[li] * douts[li];
      size_t s2 = (size_t)douts[li] * douts[li];
      WT[li][0] = p; p += s1;
      WT[li][1] = p; p += s1;
      WT[li][2] = p; p += s2;
      WT[li][3] = p; p += s2;
    }
  }
  // batched weight prep (1 launch)
  {
    WAll wa;
    int maxTotal = 0;
    for (int li = 0; li < 3; li++) {
      int e1 = dins[li] * douts[li];
      int e2 = douts[li] * douts[li];
      wa.s[li * 2 + 0] = WSeg{W[li][0], WT[li][0], WT[li][1], dins[li], douts[li], e1};
      wa.s[li * 2 + 1] = WSeg{W[li][2], WT[li][2], WT[li][3], douts[li], douts[li], e2};
      maxTotal = max(maxTotal, max(e1, e2));
    }
    dim3 g((maxTotal + 255) / 256, 6);
    wprep_all_kernel<<<g, 256, 0, stream>>>(wa);
  }

  // CSR build
  hipMemsetAsync(deg, 0, (size_t)N * sizeof(int), stream);
  hist_kernel<<<(E + 255) / 256, 256, 0, stream>>>(dst, deg, E);
  scan_kernel<<<1, 1024, 0, stream>>>(deg, rowstart, cursor, N);
  fill_kernel<<<(E + 255) / 256, 256, 0, stream>>>(src, dst, cursor, nbr, E);

  // zero all stats regions + pooled in one shot (each written later by its own layer)
  hipMemsetAsync(stats3, 0, (3 * 1024 + 64 * 512) * sizeof(float), stream);

  const int mb64 = (N + 63) / 64;
  const int mb64_8 = ((mb64 + 7) / 8) * 8;
  const int mb32 = (N + 31) / 32;
  const int mb32_8 = ((mb32 + 7) / 8) * 8;
  const int gblocks = (N + 3) / 4;

  for (int li = 0; li < 3; li++) {
    int Din = dins[li], Dout = douts[li];
    float* stats = stats3 + li * 1024;
    if (li == 0)
      gather_agg_kernel<2, false><<<gblocks, 256, 0, stream>>>(x0, rowstart, nbr, nullptr, agg, N);
    else if (li == 1)
      gather_agg_kernel<2, true><<<gblocks, 256, 0, stream>>>(h2, rowstart, nbr, stats3 + 0 * 1024, agg, N);
    else
      gather_agg_kernel<4, true><<<gblocks, 256, 0, stream>>>(h2, rowstart, nbr, stats3 + 1 * 1024, agg, N);

    if (Dout == 128) {
      // 32 rows x 128 cols, 4 waves
      gemm_mfma_kernel<32, 4><<<mb32_8, 256, 0, stream>>>(agg, WT[li][0], WT[li][1], W[li][1], h1,
                                                          N, Din, Dout, mb32, 0, 1, nullptr);
      gemm_mfma_kernel<32, 4><<<mb32_8, 256, 0, stream>>>(h1, WT[li][2], WT[li][3], W[li][3], h2,
                                                          N, Dout, Dout, mb32, 0, 0, stats);
    } else {
      // 64 rows x 256 cols, 8 waves
      int cbShift = (Dout == 256) ? 0 : 1;
      int nblocks = mb64_8 << cbShift;
      gemm_mfma_kernel<64, 8><<<nblocks, 512, 0, stream>>>(agg, WT[li][0], WT[li][1], W[li][1], h1,
                                                           N, Din, Dout, mb64, cbShift, 1, nullptr);
      gemm_mfma_kernel<64, 8><<<nblocks, 512, 0, stream>>>(h1, WT[li][2], WT[li][3], W[li][3], h2,
                                                           N, Dout, Dout, mb64, cbShift, 0, stats);
    }
    bn_prep_kernel<<<(Dout + 255) / 256, 256, 0, stream>>>(stats, W[li][4], W[li][5], Dout, 1.0f / N);
    if (li == 2) {
      bn_pool_kernel<<<64 * 8, 256, 0, stream>>>(h2, stats, batch, pooled, N);
    }
  }
  out_kernel<<<64, 64, 0, stream>>>(pooled, wo, bo, out);
}

// Round 14
// 367.037 us; speedup vs baseline: 1.2612x; 1.1977x over previous
//
#include <hip/hip_runtime.h>

typedef float f32x4 __attribute__((ext_vector_type(4)));
typedef _Float16 f16x8 __attribute__((ext_vector_type(8)));

// ================= CSR build =================
__global__ __launch_bounds__(256) void hist_kernel(const int* __restrict__ dst,
                                                   int* __restrict__ deg, int E) {
  int e = blockIdx.x * 256 + threadIdx.x;
  if (e < E) atomicAdd(&deg[dst[e]], 1);
}

__global__ __launch_bounds__(1024) void scan_kernel(const int* __restrict__ deg,
                                                    int* __restrict__ rowstart,
                                                    int* __restrict__ cursor, int N) {
  __shared__ int sums[1024];
  const int t = threadIdx.x;
  const int CH = (N + 1023) >> 10;
  int local[32];
  int base = t * CH;
  int s = 0;
  for (int i = 0; i < CH; i++) {
    int idx = base + i;
    int v = (idx < N) ? deg[idx] : 0;
    local[i] = s;
    s += v;
  }
  sums[t] = s;
  __syncthreads();
  for (int off = 1; off < 1024; off <<= 1) {
    int add = (t >= off) ? sums[t - off] : 0;
    __syncthreads();
    sums[t] += add;
    __syncthreads();
  }
  int prefix = sums[t] - s;
  for (int i = 0; i < CH; i++) {
    int idx = base + i;
    if (idx < N) {
      int v = prefix + local[i];
      rowstart[idx] = v;
      cursor[idx] = v;
    }
  }
  if (t == 1023) rowstart[N] = sums[1023];
}

__global__ __launch_bounds__(256) void fill_kernel(const int* __restrict__ src,
                                                   const int* __restrict__ dst,
                                                   int* __restrict__ cursor,
                                                   int* __restrict__ nbr, int E) {
  int e = blockIdx.x * 256 + threadIdx.x;
  if (e >= E) return;
  int pos = atomicAdd(&cursor[dst[e]], 1);
  nbr[pos] = src[e];
}

// ============ gather aggregation, optional fused BN(scale/shift)+ReLU on inputs ============
template <int C, bool BNIN>
__global__ __launch_bounds__(256) void gather_agg_kernel(
    const float* __restrict__ x, const int* __restrict__ rowstart,
    const int* __restrict__ nbr, const float* __restrict__ stats,
    float* __restrict__ agg, int N) {
  constexpr int Din = 64 * C;
  const int wave = threadIdx.x >> 6;
  const int lane = threadIdx.x & 63;
  const int node = blockIdx.x * 4 + wave;
  if (node >= N) return;

  float sc[C], sh[C];
  if constexpr (BNIN) {
#pragma unroll
    for (int j = 0; j < C; j++) {
      sc[j] = stats[lane * C + j];
      sh[j] = stats[Din + lane * C + j];
    }
  }

  float acc[C];
  {
    const float* p = x + (size_t)node * Din + lane * C;
    float v[C];
    if constexpr (C == 2) {
      float2 t = *(const float2*)p; v[0] = t.x; v[1] = t.y;
    } else {
      float4 t = *(const float4*)p; v[0] = t.x; v[1] = t.y; v[2] = t.z; v[3] = t.w;
    }
#pragma unroll
    for (int j = 0; j < C; j++)
      acc[j] = BNIN ? fmaxf(v[j] * sc[j] + sh[j], 0.f) : v[j];
  }
  const int rs = rowstart[node], re = rowstart[node + 1];
  for (int e = rs; e < re; e++) {
    int s0 = nbr[e];
    const float* p = x + (size_t)s0 * Din + lane * C;
    float v[C];
    if constexpr (C == 2) {
      float2 t = *(const float2*)p; v[0] = t.x; v[1] = t.y;
    } else {
      float4 t = *(const float4*)p; v[0] = t.x; v[1] = t.y; v[2] = t.z; v[3] = t.w;
    }
#pragma unroll
    for (int j = 0; j < C; j++)
      acc[j] += BNIN ? fmaxf(v[j] * sc[j] + sh[j], 0.f) : v[j];
  }
  float* o = agg + (size_t)node * Din + lane * C;
  if constexpr (C == 2) {
    *(float2*)o = make_float2(acc[0], acc[1]);
  } else {
    *(float4*)o = make_float4(acc[0], acc[1], acc[2], acc[3]);
  }
}

// ================= batched weight prep: W[K][N] fp32 -> WT [N][K] fp16, 6 in one launch ====
struct WSeg {
  const float* W;
  _Float16* TH;
  int K, N, total;
};
struct WAll { WSeg s[6]; };

__global__ __launch_bounds__(256) void wprep_all_kernel(WAll a) {
  WSeg sg = a.s[blockIdx.y];
  int idx = blockIdx.x * 256 + threadIdx.x;
  if (idx >= sg.total) return;
  int k = idx / sg.N, n = idx - k * sg.N;
  sg.TH[(size_t)n * sg.K + k] = (_Float16)sg.W[idx];
}

// ===== MFMA GEMM: C = A[MxK] @ B[KxN] + bias, FP16 single-pass (fp32 accumulate) =====
// r10 structure: RT rows x 128 cols per block, 4 waves (wave = 32 cols x RT rows), BK=64.
// XCD swizzle: all col-blocks of a row panel land on one XCD.
template <int RT>
__global__ __launch_bounds__(256) void gemm_mfma_kernel(
    const float* __restrict__ A, const _Float16* __restrict__ BT,
    const float* __restrict__ bias, float* __restrict__ C,
    int M, int K, int N, int mblocks, int cbShift,
    int doRelu, float* __restrict__ stats) {
  constexpr int NF = RT / 16;       // row frags per 32-K half
  constexpr int NP = RT / 32;       // staging passes per thread
  __shared__ _Float16 Ah[2 * NF * 512];
  const int bid = blockIdx.x;
  const int xcd = bid & 7;
  const int q = bid >> 3;
  const int r = ((q >> cbShift) << 3) + xcd;
  const int cb = q & ((1 << cbShift) - 1);
  if (r >= mblocks) return;

  const int tid = threadIdx.x;
  const int lane = tid & 63;
  const int w = tid >> 6;
  const int rowBase = r * RT;
  const int colBase = cb * 128 + w * 32;

  f32x4 acc[NF][2] = {};

  const int c0 = colBase + (lane & 15);
  const int kfrag = (lane >> 4) * 8;

  // r10 staging mapping
  int srow, slane, sfrag0, kk0;
  if constexpr (RT == 64) {
    srow = tid >> 2;
    const int schunk = tid & 3;
    slane = (srow & 15) | (schunk << 4);
    sfrag0 = srow >> 4;           // frag = i*NF + sfrag0, kk = schunk*8 + i*32
    kk0 = schunk * 8;
  } else {                        // RT == 32, single pass
    srow = tid >> 3;
    const int c8 = tid & 7;
    const int lc = c8 & 3, ks = c8 >> 2;
    slane = (srow & 15) | (lc << 4);
    sfrag0 = ks * NF + (srow >> 4);
    kk0 = lc * 8 + ks * 32;
  }
  const size_t arowOff = (size_t)(rowBase + srow) * K;
  const bool srowOk = (rowBase + srow) < M;

  for (int k0 = 0; k0 < K; k0 += 64) {
#pragma unroll
    for (int i = 0; i < NP; i++) {
      int kk = k0 + kk0 + (RT == 64 ? i * 32 : 0);
      float v[8];
      if (srowOk) {
        float4 a = *(const float4*)(A + arowOff + kk);
        float4 b = *(const float4*)(A + arowOff + kk + 4);
        v[0] = a.x; v[1] = a.y; v[2] = a.z; v[3] = a.w;
        v[4] = b.x; v[5] = b.y; v[6] = b.z; v[7] = b.w;
      } else {
#pragma unroll
        for (int j = 0; j < 8; j++) v[j] = 0.f;
      }
      f16x8 h8;
#pragma unroll
      for (int j = 0; j < 8; j++) h8[j] = (_Float16)v[j];
      int frag = (RT == 64 ? i * NF + sfrag0 : sfrag0);
      *(f16x8*)(Ah + frag * 512 + slane * 8) = h8;
    }
    __syncthreads();
#pragma unroll
    for (int ks = 0; ks < 2; ks++) {
      int kidx = k0 + ks * 32 + kfrag;
      f16x8 bh0 = *(const f16x8*)(BT + (size_t)c0 * K + kidx);
      f16x8 bh1 = *(const f16x8*)(BT + (size_t)(c0 + 16) * K + kidx);
#pragma unroll
      for (int fi = 0; fi < NF; fi++) {
        int frag = ks * NF + fi;
        f16x8 ah = *(const f16x8*)(Ah + frag * 512 + lane * 8);
        acc[fi][0] = __builtin_amdgcn_mfma_f32_16x16x32_f16(ah, bh0, acc[fi][0], 0, 0, 0);
        acc[fi][1] = __builtin_amdgcn_mfma_f32_16x16x32_f16(ah, bh1, acc[fi][1], 0, 0, 0);
      }
    }
    __syncthreads();
  }

  // epilogue
  const float bias0 = bias[c0], bias1 = bias[c0 + 16];
  float s1[2] = {0.f, 0.f}, s2[2] = {0.f, 0.f};
  const int rbase = rowBase + (lane >> 4) * 4;
#pragma unroll
  for (int fi = 0; fi < NF; fi++) {
#pragma unroll
    for (int j = 0; j < 4; j++) {
      int row = rbase + fi * 16 + j;
      float v0 = acc[fi][0][j] + bias0;
      float v1 = acc[fi][1][j] + bias1;
      if (doRelu) { v0 = fmaxf(v0, 0.f); v1 = fmaxf(v1, 0.f); }
      if (row < M) {
        C[(size_t)row * N + c0] = v0;
        C[(size_t)row * N + c0 + 16] = v1;
        s1[0] += v0; s2[0] += v0 * v0;
        s1[1] += v1; s2[1] += v1 * v1;
      }
    }
  }
  if (stats) {
#pragma unroll
    for (int off = 16; off < 64; off <<= 1) {
      s1[0] += __shfl_xor(s1[0], off);
      s2[0] += __shfl_xor(s2[0], off);
      s1[1] += __shfl_xor(s1[1], off);
      s2[1] += __shfl_xor(s2[1], off);
    }
    if (lane < 16) {
      atomicAdd(&stats[c0], s1[0]);
      atomicAdd(&stats[N + c0], s2[0]);
      atomicAdd(&stats[c0 + 16], s1[1]);
      atomicAdd(&stats[N + c0 + 16], s2[1]);
    }
  }
}

// ================= BN fold =================
__global__ __launch_bounds__(256) void bn_prep_kernel(float* __restrict__ stats,
                                                      const float* __restrict__ gamma,
                                                      const float* __restrict__ beta,
                                                      int D, float invN) {
  int c = blockIdx.x * 256 + threadIdx.x;
  if (c >= D) return;
  float mean = stats[c] * invN;
  float var = stats[D + c] * invN - mean * mean;
  float sc = rsqrtf(var + 1e-5f) * gamma[c];
  stats[c] = sc;
  stats[D + c] = beta[c] - mean * sc;
}

// ============ fused BN+ReLU+segment-mean pool (layer 3, D=512) ============
__global__ __launch_bounds__(256) void bn_pool_kernel(
    const float* __restrict__ h, const float* __restrict__ stats,
    const int* __restrict__ batch, float* __restrict__ pooled, int N) {
  const int g = blockIdx.x >> 3;
  const int s = blockIdx.x & 7;
  __shared__ int s_lo, s_hi;
  if (threadIdx.x == 0) {
    int lo = 0, hi = N;
    while (lo < hi) { int m = (lo + hi) >> 1; if (batch[m] < g) lo = m + 1; else hi = m; }
    s_lo = lo;
    lo = 0; hi = N;
    while (lo < hi) { int m = (lo + hi) >> 1; if (batch[m] < g + 1) lo = m + 1; else hi = m; }
    s_hi = lo;
  }
  __syncthreads();
  const int lo = s_lo, hi = s_hi, len = hi - lo;
  if (len == 0) return;
  const int per = (len + 7) >> 3;
  const int rs = lo + s * per;
  const int re = min(rs + per, hi);
  if (rs >= re) return;
  const int t = threadIdx.x;
  float2 sc = *(const float2*)(stats + 2 * t);
  float2 sh = *(const float2*)(stats + 512 + 2 * t);
  float ax = 0.f, ay = 0.f;
  for (int r = rs; r < re; r++) {
    float2 v = *(const float2*)(h + (size_t)r * 512 + 2 * t);
    ax += fmaxf(v.x * sc.x + sh.x, 0.f);
    ay += fmaxf(v.y * sc.y + sh.y, 0.f);
  }
  float inv = 1.f / (float)len;
  atomicAdd(&pooled[g * 512 + 2 * t], ax * inv);
  atomicAdd(&pooled[g * 512 + 2 * t + 1], ay * inv);
}

// ================= final projection =================
__global__ __launch_bounds__(64) void out_kernel(const float* __restrict__ pooled,
                                                 const float* __restrict__ wo,
                                                 const float* __restrict__ bo,
                                                 float* __restrict__ out) {
  int g = blockIdx.x, o = threadIdx.x;
  float acc = bo[o];
  for (int c = 0; c < 512; c++) acc += pooled[g * 512 + c] * wo[c * 64 + o];
  out[g * 64 + o] = fmaxf(acc, 0.f);
}

extern "C" void kernel_launch(void* const* d_in, const int* in_sizes, int n_in,
                              void* d_out, int out_size, void* d_ws, size_t ws_size,
                              hipStream_t stream) {
  const float* x0 = (const float*)d_in[0];
  const int* ei = (const int*)d_in[1];
  const int* batch = (const int*)d_in[2];
  const int N = in_sizes[0] / 128;
  const int E = in_sizes[1] / 2;
  const int* src = ei;
  const int* dst = ei + E;
  const float* W[3][6];
  for (int li = 0; li < 3; li++)
    for (int k = 0; k < 6; k++) W[li][k] = (const float*)d_in[3 + li * 6 + k];
  const float* wo = (const float*)d_in[21];
  const float* bo = (const float*)d_in[22];
  float* out = (float*)d_out;

  // workspace layout
  float* agg = (float*)d_ws;                 // N*256
  float* h1 = agg + (size_t)N * 256;         // N*512
  float* h2 = h1 + (size_t)N * 512;          // N*512
  float* stats3 = h2 + (size_t)N * 512;      // 3*1024
  float* pooled = stats3 + 3 * 1024;         // 64*512
  int* deg = (int*)(pooled + 64 * 512);      // N
  int* rowstart = deg + N;                   // N+1
  int* cursor = rowstart + N + 1;            // N
  int* nbr = cursor + N;                     // E
  uintptr_t wp = (uintptr_t)(nbr + E);
  wp = (wp + 15) & ~(uintptr_t)15;
  _Float16* wbuf = (_Float16*)wp;

  const int dins[3] = {128, 128, 256};
  const int douts[3] = {128, 256, 512};

  _Float16* WT[3][2];  // [li][W1, W2] fp16 transposed
  {
    _Float16* p = wbuf;
    for (int li = 0; li < 3; li++) {
      WT[li][0] = p; p += (size_t)dins[li] * douts[li];
      WT[li][1] = p; p += (size_t)douts[li] * douts[li];
    }
  }
  // batched weight prep (1 launch)
  {
    WAll wa;
    int maxTotal = 0;
    for (int li = 0; li < 3; li++) {
      int e1 = dins[li] * douts[li];
      int e2 = douts[li] * douts[li];
      wa.s[li * 2 + 0] = WSeg{W[li][0], WT[li][0], dins[li], douts[li], e1};
      wa.s[li * 2 + 1] = WSeg{W[li][2], WT[li][1], douts[li], douts[li], e2};
      maxTotal = max(maxTotal, max(e1, e2));
    }
    dim3 g((maxTotal + 255) / 256, 6);
    wprep_all_kernel<<<g, 256, 0, stream>>>(wa);
  }

  // CSR build
  hipMemsetAsync(deg, 0, (size_t)N * sizeof(int), stream);
  hist_kernel<<<(E + 255) / 256, 256, 0, stream>>>(dst, deg, E);
  scan_kernel<<<1, 1024, 0, stream>>>(deg, rowstart, cursor, N);
  fill_kernel<<<(E + 255) / 256, 256, 0, stream>>>(src, dst, cursor, nbr, E);

  // zero all stats regions + pooled in one shot
  hipMemsetAsync(stats3, 0, (3 * 1024 + 64 * 512) * sizeof(float), stream);

  const int mb64 = (N + 63) / 64;
  const int mb64_8 = ((mb64 + 7) / 8) * 8;
  const int mb32 = (N + 31) / 32;
  const int mb32_8 = ((mb32 + 7) / 8) * 8;
  const int gblocks = (N + 3) / 4;

  for (int li = 0; li < 3; li++) {
    int Din = dins[li], Dout = douts[li];
    float* stats = stats3 + li * 1024;
    if (li == 0)
      gather_agg_kernel<2, false><<<gblocks, 256, 0, stream>>>(x0, rowstart, nbr, nullptr, agg, N);
    else if (li == 1)
      gather_agg_kernel<2, true><<<gblocks, 256, 0, stream>>>(h2, rowstart, nbr, stats3 + 0 * 1024, agg, N);
    else
      gather_agg_kernel<4, true><<<gblocks, 256, 0, stream>>>(h2, rowstart, nbr, stats3 + 1 * 1024, agg, N);

    if (Dout == 128) {
      gemm_mfma_kernel<32><<<mb32_8, 256, 0, stream>>>(agg, WT[li][0], W[li][1], h1,
                                                       N, Din, Dout, mb32, 0, 1, nullptr);
      gemm_mfma_kernel<32><<<mb32_8, 256, 0, stream>>>(h1, WT[li][1], W[li][3], h2,
                                                       N, Dout, Dout, mb32, 0, 0, stats);
    } else {
      int cbShift = (Dout == 256) ? 1 : 2;
      int nblocks = mb64_8 << cbShift;
      gemm_mfma_kernel<64><<<nblocks, 256, 0, stream>>>(agg, WT[li][0], W[li][1], h1,
                                                        N, Din, Dout, mb64, cbShift, 1, nullptr);
      gemm_mfma_kernel<64><<<nblocks, 256, 0, stream>>>(h1, WT[li][1], W[li][3], h2,
                                                        N, Dout, Dout, mb64, cbShift, 0, stats);
    }
    bn_prep_kernel<<<(Dout + 255) / 256, 256, 0, stream>>>(stats, W[li][4], W[li][5], Dout, 1.0f / N);
    if (li == 2) {
      bn_pool_kernel<<<64 * 8, 256, 0, stream>>>(h2, stats, batch, pooled, N);
    }
  }
  out_kernel<<<64, 64, 0, stream>>>(pooled, wo, bo, out);
}

// Round 15
// 315.772 us; speedup vs baseline: 1.4659x; 1.1623x over previous
//
#include <hip/hip_runtime.h>

typedef float f32x4 __attribute__((ext_vector_type(4)));
typedef _Float16 f16x2 __attribute__((ext_vector_type(2)));
typedef _Float16 f16x4 __attribute__((ext_vector_type(4)));
typedef _Float16 f16x8 __attribute__((ext_vector_type(8)));

// ================= CSR build =================
__global__ __launch_bounds__(256) void hist_kernel(const int* __restrict__ dst,
                                                   int* __restrict__ deg, int E) {
  int e = blockIdx.x * 256 + threadIdx.x;
  if (e < E) atomicAdd(&deg[dst[e]], 1);
}

__global__ __launch_bounds__(1024) void scan_kernel(const int* __restrict__ deg,
                                                    int* __restrict__ rowstart,
                                                    int* __restrict__ cursor, int N) {
  __shared__ int sums[1024];
  const int t = threadIdx.x;
  const int CH = (N + 1023) >> 10;
  int local[32];
  int base = t * CH;
  int s = 0;
  for (int i = 0; i < CH; i++) {
    int idx = base + i;
    int v = (idx < N) ? deg[idx] : 0;
    local[i] = s;
    s += v;
  }
  sums[t] = s;
  __syncthreads();
  for (int off = 1; off < 1024; off <<= 1) {
    int add = (t >= off) ? sums[t - off] : 0;
    __syncthreads();
    sums[t] += add;
    __syncthreads();
  }
  int prefix = sums[t] - s;
  for (int i = 0; i < CH; i++) {
    int idx = base + i;
    if (idx < N) {
      int v = prefix + local[i];
      rowstart[idx] = v;
      cursor[idx] = v;
    }
  }
  if (t == 1023) rowstart[N] = sums[1023];
}

__global__ __launch_bounds__(256) void fill_kernel(const int* __restrict__ src,
                                                   const int* __restrict__ dst,
                                                   int* __restrict__ cursor,
                                                   int* __restrict__ nbr, int E) {
  int e = blockIdx.x * 256 + threadIdx.x;
  if (e >= E) return;
  int pos = atomicAdd(&cursor[dst[e]], 1);
  nbr[pos] = src[e];
}

// ================= x0 fp32 -> fp16 =================
__global__ __launch_bounds__(256) void xprep_kernel(const float4* __restrict__ in,
                                                    f16x4* __restrict__ out, int n4) {
  int i = blockIdx.x * 256 + threadIdx.x;
  if (i >= n4) return;
  float4 v = in[i];
  f16x4 h;
  h[0] = (_Float16)v.x; h[1] = (_Float16)v.y;
  h[2] = (_Float16)v.z; h[3] = (_Float16)v.w;
  out[i] = h;
}

// ============ gather aggregation over fp16 rows, optional fused BN+ReLU on inputs ============
// reads x (fp16, [N][Din]), writes agg (fp32) for the GEMM A-path.
template <int C, bool BNIN>
__global__ __launch_bounds__(256) void gather_agg_kernel(
    const _Float16* __restrict__ x, const int* __restrict__ rowstart,
    const int* __restrict__ nbr, const float* __restrict__ stats,
    float* __restrict__ agg, int N) {
  constexpr int Din = 64 * C;
  const int wave = threadIdx.x >> 6;
  const int lane = threadIdx.x & 63;
  const int node = blockIdx.x * 4 + wave;
  if (node >= N) return;

  float sc[C], sh[C];
  if constexpr (BNIN) {
#pragma unroll
    for (int j = 0; j < C; j++) {
      sc[j] = stats[lane * C + j];
      sh[j] = stats[Din + lane * C + j];
    }
  }

#define LOADROW(dstv, rowidx)                                              \
  {                                                                        \
    const _Float16* _p = x + (size_t)(rowidx)*Din + lane * C;              \
    if constexpr (C == 2) {                                                \
      f16x2 _t = *(const f16x2*)_p;                                        \
      dstv[0] = (float)_t[0]; dstv[1] = (float)_t[1];                      \
    } else {                                                               \
      f16x4 _t = *(const f16x4*)_p;                                        \
      dstv[0] = (float)_t[0]; dstv[1] = (float)_t[1];                      \
      dstv[2] = (float)_t[2]; dstv[3] = (float)_t[3];                      \
    }                                                                      \
  }

  float acc[C];
  {
    float v[C];
    LOADROW(v, node)
#pragma unroll
    for (int j = 0; j < C; j++)
      acc[j] = BNIN ? fmaxf(v[j] * sc[j] + sh[j], 0.f) : v[j];
  }
  const int rs = rowstart[node], re = rowstart[node + 1];
  int e = rs;
  for (; e + 1 < re; e += 2) {
    int s0 = nbr[e], s1 = nbr[e + 1];
    float v0[C], v1[C];
    LOADROW(v0, s0)
    LOADROW(v1, s1)
#pragma unroll
    for (int j = 0; j < C; j++) {
      acc[j] += BNIN ? fmaxf(v0[j] * sc[j] + sh[j], 0.f) : v0[j];
      acc[j] += BNIN ? fmaxf(v1[j] * sc[j] + sh[j], 0.f) : v1[j];
    }
  }
  if (e < re) {
    int s0 = nbr[e];
    float v0[C];
    LOADROW(v0, s0)
#pragma unroll
    for (int j = 0; j < C; j++)
      acc[j] += BNIN ? fmaxf(v0[j] * sc[j] + sh[j], 0.f) : v0[j];
  }
#undef LOADROW

  float* o = agg + (size_t)node * Din + lane * C;
  if constexpr (C == 2) {
    *(float2*)o = make_float2(acc[0], acc[1]);
  } else {
    *(float4*)o = make_float4(acc[0], acc[1], acc[2], acc[3]);
  }
}

// ================= batched weight prep: W[K][N] fp32 -> WT [N][K] fp16, 6 in one launch ====
struct WSeg {
  const float* W;
  _Float16* TH;
  int K, N, total;
};
struct WAll { WSeg s[6]; };

__global__ __launch_bounds__(256) void wprep_all_kernel(WAll a) {
  WSeg sg = a.s[blockIdx.y];
  int idx = blockIdx.x * 256 + threadIdx.x;
  if (idx >= sg.total) return;
  int k = idx / sg.N, n = idx - k * sg.N;
  sg.TH[(size_t)n * sg.K + k] = (_Float16)sg.W[idx];
}

// ===== MFMA GEMM: C = A[MxK] @ B[KxN] + bias, FP16 single-pass (fp32 accumulate) =====
// r10 structure: RT rows x 128 cols per block, 4 waves (wave = 32 cols x RT rows), BK=64.
// Output: fp32 (Ch==nullptr) or fp16 (Ch) with fp32 BN-stats.
template <int RT>
__global__ __launch_bounds__(256) void gemm_mfma_kernel(
    const float* __restrict__ A, const _Float16* __restrict__ BT,
    const float* __restrict__ bias, float* __restrict__ C,
    _Float16* __restrict__ Ch,
    int M, int K, int N, int mblocks, int cbShift,
    int doRelu, float* __restrict__ stats) {
  constexpr int NF = RT / 16;
  constexpr int NP = RT / 32;
  __shared__ _Float16 Ah[2 * NF * 512];
  const int bid = blockIdx.x;
  const int xcd = bid & 7;
  const int q = bid >> 3;
  const int r = ((q >> cbShift) << 3) + xcd;
  const int cb = q & ((1 << cbShift) - 1);
  if (r >= mblocks) return;

  const int tid = threadIdx.x;
  const int lane = tid & 63;
  const int w = tid >> 6;
  const int rowBase = r * RT;
  const int colBase = cb * 128 + w * 32;

  f32x4 acc[NF][2] = {};

  const int c0 = colBase + (lane & 15);
  const int kfrag = (lane >> 4) * 8;

  // r10 staging mapping
  int srow, slane, sfrag0, kk0;
  if constexpr (RT == 64) {
    srow = tid >> 2;
    const int schunk = tid & 3;
    slane = (srow & 15) | (schunk << 4);
    sfrag0 = srow >> 4;
    kk0 = schunk * 8;
  } else {
    srow = tid >> 3;
    const int c8 = tid & 7;
    const int lc = c8 & 3, ks = c8 >> 2;
    slane = (srow & 15) | (lc << 4);
    sfrag0 = ks * NF + (srow >> 4);
    kk0 = lc * 8 + ks * 32;
  }
  const size_t arowOff = (size_t)(rowBase + srow) * K;
  const bool srowOk = (rowBase + srow) < M;

  for (int k0 = 0; k0 < K; k0 += 64) {
#pragma unroll
    for (int i = 0; i < NP; i++) {
      int kk = k0 + kk0 + (RT == 64 ? i * 32 : 0);
      float v[8];
      if (srowOk) {
        float4 a = *(const float4*)(A + arowOff + kk);
        float4 b = *(const float4*)(A + arowOff + kk + 4);
        v[0] = a.x; v[1] = a.y; v[2] = a.z; v[3] = a.w;
        v[4] = b.x; v[5] = b.y; v[6] = b.z; v[7] = b.w;
      } else {
#pragma unroll
        for (int j = 0; j < 8; j++) v[j] = 0.f;
      }
      f16x8 h8;
#pragma unroll
      for (int j = 0; j < 8; j++) h8[j] = (_Float16)v[j];
      int frag = (RT == 64 ? i * NF + sfrag0 : sfrag0);
      *(f16x8*)(Ah + frag * 512 + slane * 8) = h8;
    }
    __syncthreads();
#pragma unroll
    for (int ks = 0; ks < 2; ks++) {
      int kidx = k0 + ks * 32 + kfrag;
      f16x8 bh0 = *(const f16x8*)(BT + (size_t)c0 * K + kidx);
      f16x8 bh1 = *(const f16x8*)(BT + (size_t)(c0 + 16) * K + kidx);
#pragma unroll
      for (int fi = 0; fi < NF; fi++) {
        int frag = ks * NF + fi;
        f16x8 ah = *(const f16x8*)(Ah + frag * 512 + lane * 8);
        acc[fi][0] = __builtin_amdgcn_mfma_f32_16x16x32_f16(ah, bh0, acc[fi][0], 0, 0, 0);
        acc[fi][1] = __builtin_amdgcn_mfma_f32_16x16x32_f16(ah, bh1, acc[fi][1], 0, 0, 0);
      }
    }
    __syncthreads();
  }

  // epilogue
  const float bias0 = bias[c0], bias1 = bias[c0 + 16];
  float s1[2] = {0.f, 0.f}, s2[2] = {0.f, 0.f};
  const int rbase = rowBase + (lane >> 4) * 4;
#pragma unroll
  for (int fi = 0; fi < NF; fi++) {
#pragma unroll
    for (int j = 0; j < 4; j++) {
      int row = rbase + fi * 16 + j;
      float v0 = acc[fi][0][j] + bias0;
      float v1 = acc[fi][1][j] + bias1;
      if (doRelu) { v0 = fmaxf(v0, 0.f); v1 = fmaxf(v1, 0.f); }
      if (row < M) {
        if (Ch) {
          Ch[(size_t)row * N + c0] = (_Float16)v0;
          Ch[(size_t)row * N + c0 + 16] = (_Float16)v1;
        } else {
          C[(size_t)row * N + c0] = v0;
          C[(size_t)row * N + c0 + 16] = v1;
        }
        s1[0] += v0; s2[0] += v0 * v0;
        s1[1] += v1; s2[1] += v1 * v1;
      }
    }
  }
  if (stats) {
#pragma unroll
    for (int off = 16; off < 64; off <<= 1) {
      s1[0] += __shfl_xor(s1[0], off);
      s2[0] += __shfl_xor(s2[0], off);
      s1[1] += __shfl_xor(s1[1], off);
      s2[1] += __shfl_xor(s2[1], off);
    }
    if (lane < 16) {
      atomicAdd(&stats[c0], s1[0]);
      atomicAdd(&stats[N + c0], s2[0]);
      atomicAdd(&stats[c0 + 16], s1[1]);
      atomicAdd(&stats[N + c0 + 16], s2[1]);
    }
  }
}

// ================= BN fold =================
__global__ __launch_bounds__(256) void bn_prep_kernel(float* __restrict__ stats,
                                                      const float* __restrict__ gamma,
                                                      const float* __restrict__ beta,
                                                      int D, float invN) {
  int c = blockIdx.x * 256 + threadIdx.x;
  if (c >= D) return;
  float mean = stats[c] * invN;
  float var = stats[D + c] * invN - mean * mean;
  float sc = rsqrtf(var + 1e-5f) * gamma[c];
  stats[c] = sc;
  stats[D + c] = beta[c] - mean * sc;
}

// ============ fused BN+ReLU+segment-mean pool (layer 3, D=512, fp16 input) ============
__global__ __launch_bounds__(256) void bn_pool_kernel(
    const _Float16* __restrict__ h, const float* __restrict__ stats,
    const int* __restrict__ batch, float* __restrict__ pooled, int N) {
  const int g = blockIdx.x >> 3;
  const int s = blockIdx.x & 7;
  __shared__ int s_lo, s_hi;
  if (threadIdx.x == 0) {
    int lo = 0, hi = N;
    while (lo < hi) { int m = (lo + hi) >> 1; if (batch[m] < g) lo = m + 1; else hi = m; }
    s_lo = lo;
    lo = 0; hi = N;
    while (lo < hi) { int m = (lo + hi) >> 1; if (batch[m] < g + 1) lo = m + 1; else hi = m; }
    s_hi = lo;
  }
  __syncthreads();
  const int lo = s_lo, hi = s_hi, len = hi - lo;
  if (len == 0) return;
  const int per = (len + 7) >> 3;
  const int rs = lo + s * per;
  const int re = min(rs + per, hi);
  if (rs >= re) return;
  const int t = threadIdx.x;
  float2 sc = *(const float2*)(stats + 2 * t);
  float2 sh = *(const float2*)(stats + 512 + 2 * t);
  float ax = 0.f, ay = 0.f;
  for (int r = rs; r < re; r++) {
    f16x2 v = *(const f16x2*)(h + (size_t)r * 512 + 2 * t);
    ax += fmaxf((float)v[0] * sc.x + sh.x, 0.f);
    ay += fmaxf((float)v[1] * sc.y + sh.y, 0.f);
  }
  float inv = 1.f / (float)len;
  atomicAdd(&pooled[g * 512 + 2 * t], ax * inv);
  atomicAdd(&pooled[g * 512 + 2 * t + 1], ay * inv);
}

// ================= final projection =================
__global__ __launch_bounds__(64) void out_kernel(const float* __restrict__ pooled,
                                                 const float* __restrict__ wo,
                                                 const float* __restrict__ bo,
                                                 float* __restrict__ out) {
  int g = blockIdx.x, o = threadIdx.x;
  float acc = bo[o];
  for (int c = 0; c < 512; c++) acc += pooled[g * 512 + c] * wo[c * 64 + o];
  out[g * 64 + o] = fmaxf(acc, 0.f);
}

extern "C" void kernel_launch(void* const* d_in, const int* in_sizes, int n_in,
                              void* d_out, int out_size, void* d_ws, size_t ws_size,
                              hipStream_t stream) {
  const float* x0 = (const float*)d_in[0];
  const int* ei = (const int*)d_in[1];
  const int* batch = (const int*)d_in[2];
  const int N = in_sizes[0] / 128;
  const int E = in_sizes[1] / 2;
  const int* src = ei;
  const int* dst = ei + E;
  const float* W[3][6];
  for (int li = 0; li < 3; li++)
    for (int k = 0; k < 6; k++) W[li][k] = (const float*)d_in[3 + li * 6 + k];
  const float* wo = (const float*)d_in[21];
  const float* bo = (const float*)d_in[22];
  float* out = (float*)d_out;

  // workspace layout
  float* agg = (float*)d_ws;                 // N*256 f32
  float* h1 = agg + (size_t)N * 256;         // N*512 f32
  float* stats3 = h1 + (size_t)N * 512;      // 3*1024
  float* pooled = stats3 + 3 * 1024;         // 64*512
  int* deg = (int*)(pooled + 64 * 512);      // N
  int* rowstart = deg + N;                   // N+1
  int* cursor = rowstart + N + 1;            // N
  int* nbr = cursor + N;                     // E
  uintptr_t wp = (uintptr_t)(nbr + E);
  wp = (wp + 15) & ~(uintptr_t)15;
  _Float16* h2h = (_Float16*)wp;             // N*512 f16 (pre-BN activations)
  _Float16* x0h = h2h + (size_t)N * 512;     // N*128 f16
  _Float16* wbuf = x0h + (size_t)N * 128;

  const int dins[3] = {128, 128, 256};
  const int douts[3] = {128, 256, 512};

  _Float16* WT[3][2];
  {
    _Float16* p = wbuf;
    for (int li = 0; li < 3; li++) {
      WT[li][0] = p; p += (size_t)dins[li] * douts[li];
      WT[li][1] = p; p += (size_t)douts[li] * douts[li];
    }
  }
  // batched weight prep (1 launch)
  {
    WAll wa;
    int maxTotal = 0;
    for (int li = 0; li < 3; li++) {
      int e1 = dins[li] * douts[li];
      int e2 = douts[li] * douts[li];
      wa.s[li * 2 + 0] = WSeg{W[li][0], WT[li][0], dins[li], douts[li], e1};
      wa.s[li * 2 + 1] = WSeg{W[li][2], WT[li][1], douts[li], douts[li], e2};
      maxTotal = max(maxTotal, max(e1, e2));
    }
    dim3 g((maxTotal + 255) / 256, 6);
    wprep_all_kernel<<<g, 256, 0, stream>>>(wa);
  }

  // x0 -> fp16
  {
    int n4 = N * 32;  // N*128/4
    xprep_kernel<<<(n4 + 255) / 256, 256, 0, stream>>>((const float4*)x0, (f16x4*)x0h, n4);
  }

  // CSR build
  hipMemsetAsync(deg, 0, (size_t)N * sizeof(int), stream);
  hist_kernel<<<(E + 255) / 256, 256, 0, stream>>>(dst, deg, E);
  scan_kernel<<<1, 1024, 0, stream>>>(deg, rowstart, cursor, N);
  fill_kernel<<<(E + 255) / 256, 256, 0, stream>>>(src, dst, cursor, nbr, E);

  // zero stats + pooled in one shot
  hipMemsetAsync(stats3, 0, (3 * 1024 + 64 * 512) * sizeof(float), stream);

  const int mb64 = (N + 63) / 64;
  const int mb64_8 = ((mb64 + 7) / 8) * 8;
  const int mb32 = (N + 31) / 32;
  const int mb32_8 = ((mb32 + 7) / 8) * 8;
  const int gblocks = (N + 3) / 4;

  for (int li = 0; li < 3; li++) {
    int Din = dins[li], Dout = douts[li];
    float* stats = stats3 + li * 1024;
    if (li == 0)
      gather_agg_kernel<2, false><<<gblocks, 256, 0, stream>>>(x0h, rowstart, nbr, nullptr, agg, N);
    else if (li == 1)
      gather_agg_kernel<2, true><<<gblocks, 256, 0, stream>>>(h2h, rowstart, nbr, stats3 + 0 * 1024, agg, N);
    else
      gather_agg_kernel<4, true><<<gblocks, 256, 0, stream>>>(h2h, rowstart, nbr, stats3 + 1 * 1024, agg, N);

    if (Dout == 128) {
      gemm_mfma_kernel<32><<<mb32_8, 256, 0, stream>>>(agg, WT[li][0], W[li][1], h1, nullptr,
                                                       N, Din, Dout, mb32, 0, 1, nullptr);
      gemm_mfma_kernel<32><<<mb32_8, 256, 0, stream>>>(h1, WT[li][1], W[li][3], nullptr, h2h,
                                                       N, Dout, Dout, mb32, 0, 0, stats);
    } else {
      int cbShift = (Dout == 256) ? 1 : 2;
      int nblocks = mb64_8 << cbShift;
      gemm_mfma_kernel<64><<<nblocks, 256, 0, stream>>>(agg, WT[li][0], W[li][1], h1, nullptr,
                                                        N, Din, Dout, mb64, cbShift, 1, nullptr);
      gemm_mfma_kernel<64><<<nblocks, 256, 0, stream>>>(h1, WT[li][1], W[li][3], nullptr, h2h,
                                                        N, Dout, Dout, mb64, cbShift, 0, stats);
    }
    bn_prep_kernel<<<(Dout + 255) / 256, 256, 0, stream>>>(stats, W[li][4], W[li][5], Dout, 1.0f / N);
    if (li == 2) {
      bn_pool_kernel<<<64 * 8, 256, 0, stream>>>(h2h, stats, batch, pooled, N);
    }
  }
  out_kernel<<<64, 64, 0, stream>>>(pooled, wo, bo, out);
}

// Round 16
// 310.221 us; speedup vs baseline: 1.4922x; 1.0179x over previous
//
#include <hip/hip_runtime.h>

typedef float f32x4 __attribute__((ext_vector_type(4)));
typedef _Float16 f16x2 __attribute__((ext_vector_type(2)));
typedef _Float16 f16x4 __attribute__((ext_vector_type(4)));
typedef _Float16 f16x8 __attribute__((ext_vector_type(8)));

// ================= CSR build =================
__global__ __launch_bounds__(256) void hist_kernel(const int* __restrict__ dst,
                                                   int* __restrict__ deg, int E) {
  int e = blockIdx.x * 256 + threadIdx.x;
  if (e < E) atomicAdd(&deg[dst[e]], 1);
}

__global__ __launch_bounds__(1024) void scan_kernel(const int* __restrict__ deg,
                                                    int* __restrict__ rowstart,
                                                    int* __restrict__ cursor, int N) {
  __shared__ int sums[1024];
  const int t = threadIdx.x;
  const int CH = (N + 1023) >> 10;
  int local[32];
  int base = t * CH;
  int s = 0;
  for (int i = 0; i < CH; i++) {
    int idx = base + i;
    int v = (idx < N) ? deg[idx] : 0;
    local[i] = s;
    s += v;
  }
  sums[t] = s;
  __syncthreads();
  for (int off = 1; off < 1024; off <<= 1) {
    int add = (t >= off) ? sums[t - off] : 0;
    __syncthreads();
    sums[t] += add;
    __syncthreads();
  }
  int prefix = sums[t] - s;
  for (int i = 0; i < CH; i++) {
    int idx = base + i;
    if (idx < N) {
      int v = prefix + local[i];
      rowstart[idx] = v;
      cursor[idx] = v;
    }
  }
  if (t == 1023) rowstart[N] = sums[1023];
}

__global__ __launch_bounds__(256) void fill_kernel(const int* __restrict__ src,
                                                   const int* __restrict__ dst,
                                                   int* __restrict__ cursor,
                                                   int* __restrict__ nbr, int E) {
  int e = blockIdx.x * 256 + threadIdx.x;
  if (e >= E) return;
  int pos = atomicAdd(&cursor[dst[e]], 1);
  nbr[pos] = src[e];
}

// ================= x0 fp32 -> fp16 =================
__global__ __launch_bounds__(256) void xprep_kernel(const float4* __restrict__ in,
                                                    f16x4* __restrict__ out, int n4) {
  int i = blockIdx.x * 256 + threadIdx.x;
  if (i >= n4) return;
  float4 v = in[i];
  f16x4 h;
  h[0] = (_Float16)v.x; h[1] = (_Float16)v.y;
  h[2] = (_Float16)v.z; h[3] = (_Float16)v.w;
  out[i] = h;
}

// ============ gather aggregation over fp16 rows, fused BN+ReLU on inputs; fp16 output ========
template <int C, bool BNIN>
__global__ __launch_bounds__(256) void gather_agg_kernel(
    const _Float16* __restrict__ x, const int* __restrict__ rowstart,
    const int* __restrict__ nbr, const float* __restrict__ stats,
    _Float16* __restrict__ agg, int N) {
  constexpr int Din = 64 * C;
  const int wave = threadIdx.x >> 6;
  const int lane = threadIdx.x & 63;
  const int node = blockIdx.x * 4 + wave;
  if (node >= N) return;

  float sc[C], sh[C];
  if constexpr (BNIN) {
#pragma unroll
    for (int j = 0; j < C; j++) {
      sc[j] = stats[lane * C + j];
      sh[j] = stats[Din + lane * C + j];
    }
  }

#define LOADROW(dstv, rowidx)                                              \
  {                                                                        \
    const _Float16* _p = x + (size_t)(rowidx)*Din + lane * C;              \
    if constexpr (C == 2) {                                                \
      f16x2 _t = *(const f16x2*)_p;                                        \
      dstv[0] = (float)_t[0]; dstv[1] = (float)_t[1];                      \
    } else {                                                               \
      f16x4 _t = *(const f16x4*)_p;                                        \
      dstv[0] = (float)_t[0]; dstv[1] = (float)_t[1];                      \
      dstv[2] = (float)_t[2]; dstv[3] = (float)_t[3];                      \
    }                                                                      \
  }

  float acc[C];
  {
    float v[C];
    LOADROW(v, node)
#pragma unroll
    for (int j = 0; j < C; j++)
      acc[j] = BNIN ? fmaxf(v[j] * sc[j] + sh[j], 0.f) : v[j];
  }
  const int rs = rowstart[node], re = rowstart[node + 1];
  int e = rs;
  for (; e + 1 < re; e += 2) {
    int s0 = nbr[e], s1 = nbr[e + 1];
    float v0[C], v1[C];
    LOADROW(v0, s0)
    LOADROW(v1, s1)
#pragma unroll
    for (int j = 0; j < C; j++) {
      acc[j] += BNIN ? fmaxf(v0[j] * sc[j] + sh[j], 0.f) : v0[j];
      acc[j] += BNIN ? fmaxf(v1[j] * sc[j] + sh[j], 0.f) : v1[j];
    }
  }
  if (e < re) {
    int s0 = nbr[e];
    float v0[C];
    LOADROW(v0, s0)
#pragma unroll
    for (int j = 0; j < C; j++)
      acc[j] += BNIN ? fmaxf(v0[j] * sc[j] + sh[j], 0.f) : v0[j];
  }
#undef LOADROW

  _Float16* o = agg + (size_t)node * Din + lane * C;
  if constexpr (C == 2) {
    f16x2 r; r[0] = (_Float16)acc[0]; r[1] = (_Float16)acc[1];
    *(f16x2*)o = r;
  } else {
    f16x4 r;
    r[0] = (_Float16)acc[0]; r[1] = (_Float16)acc[1];
    r[2] = (_Float16)acc[2]; r[3] = (_Float16)acc[3];
    *(f16x4*)o = r;
  }
}

// ================= batched weight prep: W[K][N] fp32 -> WT [N][K] fp16, 6 in one launch ====
struct WSeg {
  const float* W;
  _Float16* TH;
  int K, N, total;
};
struct WAll { WSeg s[6]; };

__global__ __launch_bounds__(256) void wprep_all_kernel(WAll a) {
  WSeg sg = a.s[blockIdx.y];
  int idx = blockIdx.x * 256 + threadIdx.x;
  if (idx >= sg.total) return;
  int k = idx / sg.N, n = idx - k * sg.N;
  sg.TH[(size_t)n * sg.K + k] = (_Float16)sg.W[idx];
}

// ===== MFMA GEMM: C = A[MxK] @ B[KxN] + bias, all-FP16 inputs (fp32 accumulate) =====
// r10 structure: RT rows x 128 cols per block, 4 waves (wave = 32 cols x RT rows), BK=64.
// A is fp16: staging is a pure 16B load + ds_write_b128 (no conversion).
// Output fp16 + optional fp32 BN-stats. XCD swizzle keeps a row panel on one XCD.
template <int RT>
__global__ __launch_bounds__(256, 8) void gemm_mfma_kernel(
    const _Float16* __restrict__ A, const _Float16* __restrict__ BT,
    const float* __restrict__ bias, _Float16* __restrict__ Ch,
    int M, int K, int N, int mblocks, int cbShift,
    int doRelu, float* __restrict__ stats) {
  constexpr int NF = RT / 16;       // row frags per 32-K half
  constexpr int NP = RT / 32;       // staging passes per thread
  __shared__ _Float16 Ah[2 * NF * 512];
  const int bid = blockIdx.x;
  const int xcd = bid & 7;
  const int q = bid >> 3;
  const int r = ((q >> cbShift) << 3) + xcd;
  const int cb = q & ((1 << cbShift) - 1);
  if (r >= mblocks) return;

  const int tid = threadIdx.x;
  const int lane = tid & 63;
  const int w = tid >> 6;
  const int rowBase = r * RT;
  const int colBase = cb * 128 + w * 32;

  f32x4 acc[NF][2] = {};

  const int c0 = colBase + (lane & 15);
  const int kfrag = (lane >> 4) * 8;

  // r10 staging mapping (identical thread->LDS map, fp16 payload)
  int srow, slane, sfrag0, kk0;
  if constexpr (RT == 64) {
    srow = tid >> 2;
    const int schunk = tid & 3;
    slane = (srow & 15) | (schunk << 4);
    sfrag0 = srow >> 4;
    kk0 = schunk * 8;
  } else {
    srow = tid >> 3;
    const int c8 = tid & 7;
    const int lc = c8 & 3, ks = c8 >> 2;
    slane = (srow & 15) | (lc << 4);
    sfrag0 = ks * NF + (srow >> 4);
    kk0 = lc * 8 + ks * 32;
  }
  const size_t arowOff = (size_t)(rowBase + srow) * K;
  const bool srowOk = (rowBase + srow) < M;

  for (int k0 = 0; k0 < K; k0 += 64) {
#pragma unroll
    for (int i = 0; i < NP; i++) {
      int kk = k0 + kk0 + (RT == 64 ? i * 32 : 0);
      f16x8 h8 = {};
      if (srowOk) h8 = *(const f16x8*)(A + arowOff + kk);
      int frag = (RT == 64 ? i * NF + sfrag0 : sfrag0);
      *(f16x8*)(Ah + frag * 512 + slane * 8) = h8;
    }
    __syncthreads();
#pragma unroll
    for (int ks = 0; ks < 2; ks++) {
      int kidx = k0 + ks * 32 + kfrag;
      f16x8 bh0 = *(const f16x8*)(BT + (size_t)c0 * K + kidx);
      f16x8 bh1 = *(const f16x8*)(BT + (size_t)(c0 + 16) * K + kidx);
#pragma unroll
      for (int fi = 0; fi < NF; fi++) {
        int frag = ks * NF + fi;
        f16x8 ah = *(const f16x8*)(Ah + frag * 512 + lane * 8);
        acc[fi][0] = __builtin_amdgcn_mfma_f32_16x16x32_f16(ah, bh0, acc[fi][0], 0, 0, 0);
        acc[fi][1] = __builtin_amdgcn_mfma_f32_16x16x32_f16(ah, bh1, acc[fi][1], 0, 0, 0);
      }
    }
    __syncthreads();
  }

  // epilogue
  const float bias0 = bias[c0], bias1 = bias[c0 + 16];
  float s1[2] = {0.f, 0.f}, s2[2] = {0.f, 0.f};
  const int rbase = rowBase + (lane >> 4) * 4;
#pragma unroll
  for (int fi = 0; fi < NF; fi++) {
#pragma unroll
    for (int j = 0; j < 4; j++) {
      int row = rbase + fi * 16 + j;
      float v0 = acc[fi][0][j] + bias0;
      float v1 = acc[fi][1][j] + bias1;
      if (doRelu) { v0 = fmaxf(v0, 0.f); v1 = fmaxf(v1, 0.f); }
      if (row < M) {
        Ch[(size_t)row * N + c0] = (_Float16)v0;
        Ch[(size_t)row * N + c0 + 16] = (_Float16)v1;
        s1[0] += v0; s2[0] += v0 * v0;
        s1[1] += v1; s2[1] += v1 * v1;
      }
    }
  }
  if (stats) {
#pragma unroll
    for (int off = 16; off < 64; off <<= 1) {
      s1[0] += __shfl_xor(s1[0], off);
      s2[0] += __shfl_xor(s2[0], off);
      s1[1] += __shfl_xor(s1[1], off);
      s2[1] += __shfl_xor(s2[1], off);
    }
    if (lane < 16) {
      atomicAdd(&stats[c0], s1[0]);
      atomicAdd(&stats[N + c0], s2[0]);
      atomicAdd(&stats[c0 + 16], s1[1]);
      atomicAdd(&stats[N + c0 + 16], s2[1]);
    }
  }
}

// ================= BN fold =================
__global__ __launch_bounds__(256) void bn_prep_kernel(float* __restrict__ stats,
                                                      const float* __restrict__ gamma,
                                                      const float* __restrict__ beta,
                                                      int D, float invN) {
  int c = blockIdx.x * 256 + threadIdx.x;
  if (c >= D) return;
  float mean = stats[c] * invN;
  float var = stats[D + c] * invN - mean * mean;
  float sc = rsqrtf(var + 1e-5f) * gamma[c];
  stats[c] = sc;
  stats[D + c] = beta[c] - mean * sc;
}

// ============ fused BN+ReLU+segment-mean pool (layer 3, D=512, fp16 input) ============
__global__ __launch_bounds__(256) void bn_pool_kernel(
    const _Float16* __restrict__ h, const float* __restrict__ stats,
    const int* __restrict__ batch, float* __restrict__ pooled, int N) {
  const int g = blockIdx.x >> 3;
  const int s = blockIdx.x & 7;
  __shared__ int s_lo, s_hi;
  if (threadIdx.x == 0) {
    int lo = 0, hi = N;
    while (lo < hi) { int m = (lo + hi) >> 1; if (batch[m] < g) lo = m + 1; else hi = m; }
    s_lo = lo;
    lo = 0; hi = N;
    while (lo < hi) { int m = (lo + hi) >> 1; if (batch[m] < g + 1) lo = m + 1; else hi = m; }
    s_hi = lo;
  }
  __syncthreads();
  const int lo = s_lo, hi = s_hi, len = hi - lo;
  if (len == 0) return;
  const int per = (len + 7) >> 3;
  const int rs = lo + s * per;
  const int re = min(rs + per, hi);
  if (rs >= re) return;
  const int t = threadIdx.x;
  float2 sc = *(const float2*)(stats + 2 * t);
  float2 sh = *(const float2*)(stats + 512 + 2 * t);
  float ax = 0.f, ay = 0.f;
  for (int r = rs; r < re; r++) {
    f16x2 v = *(const f16x2*)(h + (size_t)r * 512 + 2 * t);
    ax += fmaxf((float)v[0] * sc.x + sh.x, 0.f);
    ay += fmaxf((float)v[1] * sc.y + sh.y, 0.f);
  }
  float inv = 1.f / (float)len;
  atomicAdd(&pooled[g * 512 + 2 * t], ax * inv);
  atomicAdd(&pooled[g * 512 + 2 * t + 1], ay * inv);
}

// ================= final projection =================
__global__ __launch_bounds__(64) void out_kernel(const float* __restrict__ pooled,
                                                 const float* __restrict__ wo,
                                                 const float* __restrict__ bo,
                                                 float* __restrict__ out) {
  int g = blockIdx.x, o = threadIdx.x;
  float acc = bo[o];
  for (int c = 0; c < 512; c++) acc += pooled[g * 512 + c] * wo[c * 64 + o];
  out[g * 64 + o] = fmaxf(acc, 0.f);
}

extern "C" void kernel_launch(void* const* d_in, const int* in_sizes, int n_in,
                              void* d_out, int out_size, void* d_ws, size_t ws_size,
                              hipStream_t stream) {
  const float* x0 = (const float*)d_in[0];
  const int* ei = (const int*)d_in[1];
  const int* batch = (const int*)d_in[2];
  const int N = in_sizes[0] / 128;
  const int E = in_sizes[1] / 2;
  const int* src = ei;
  const int* dst = ei + E;
  const float* W[3][6];
  for (int li = 0; li < 3; li++)
    for (int k = 0; k < 6; k++) W[li][k] = (const float*)d_in[3 + li * 6 + k];
  const float* wo = (const float*)d_in[21];
  const float* bo = (const float*)d_in[22];
  float* out = (float*)d_out;

  // workspace layout
  float* stats3 = (float*)d_ws;              // 3*1024
  float* pooled = stats3 + 3 * 1024;         // 64*512
  int* deg = (int*)(pooled + 64 * 512);      // N
  int* rowstart = deg + N;                   // N+1
  int* cursor = rowstart + N + 1;            // N
  int* nbr = cursor + N;                     // E
  uintptr_t wp = (uintptr_t)(nbr + E);
  wp = (wp + 15) & ~(uintptr_t)15;
  _Float16* aggh = (_Float16*)wp;            // N*256 f16
  _Float16* h1h = aggh + (size_t)N * 256;    // N*512 f16
  _Float16* h2h = h1h + (size_t)N * 512;     // N*512 f16
  _Float16* x0h = h2h + (size_t)N * 512;     // N*128 f16
  _Float16* wbuf = x0h + (size_t)N * 128;

  const int dins[3] = {128, 128, 256};
  const int douts[3] = {128, 256, 512};

  _Float16* WT[3][2];
  {
    _Float16* p = wbuf;
    for (int li = 0; li < 3; li++) {
      WT[li][0] = p; p += (size_t)dins[li] * douts[li];
      WT[li][1] = p; p += (size_t)douts[li] * douts[li];
    }
  }
  // batched weight prep (1 launch)
  {
    WAll wa;
    int maxTotal = 0;
    for (int li = 0; li < 3; li++) {
      int e1 = dins[li] * douts[li];
      int e2 = douts[li] * douts[li];
      wa.s[li * 2 + 0] = WSeg{W[li][0], WT[li][0], dins[li], douts[li], e1};
      wa.s[li * 2 + 1] = WSeg{W[li][2], WT[li][1], douts[li], douts[li], e2};
      maxTotal = max(maxTotal, max(e1, e2));
    }
    dim3 g((maxTotal + 255) / 256, 6);
    wprep_all_kernel<<<g, 256, 0, stream>>>(wa);
  }

  // x0 -> fp16
  {
    int n4 = N * 32;  // N*128/4
    xprep_kernel<<<(n4 + 255) / 256, 256, 0, stream>>>((const float4*)x0, (f16x4*)x0h, n4);
  }

  // CSR build
  hipMemsetAsync(deg, 0, (size_t)N * sizeof(int), stream);
  hist_kernel<<<(E + 255) / 256, 256, 0, stream>>>(dst, deg, E);
  scan_kernel<<<1, 1024, 0, stream>>>(deg, rowstart, cursor, N);
  fill_kernel<<<(E + 255) / 256, 256, 0, stream>>>(src, dst, cursor, nbr, E);

  // zero stats + pooled in one shot
  hipMemsetAsync(stats3, 0, (3 * 1024 + 64 * 512) * sizeof(float), stream);

  const int mb64 = (N + 63) / 64;
  const int mb64_8 = ((mb64 + 7) / 8) * 8;
  const int mb32 = (N + 31) / 32;
  const int mb32_8 = ((mb32 + 7) / 8) * 8;
  const int gblocks = (N + 3) / 4;

  for (int li = 0; li < 3; li++) {
    int Din = dins[li], Dout = douts[li];
    float* stats = stats3 + li * 1024;
    if (li == 0)
      gather_agg_kernel<2, false><<<gblocks, 256, 0, stream>>>(x0h, rowstart, nbr, nullptr, aggh, N);
    else if (li == 1)
      gather_agg_kernel<2, true><<<gblocks, 256, 0, stream>>>(h2h, rowstart, nbr, stats3 + 0 * 1024, aggh, N);
    else
      gather_agg_kernel<4, true><<<gblocks, 256, 0, stream>>>(h2h, rowstart, nbr, stats3 + 1 * 1024, aggh, N);

    if (Dout == 128) {
      gemm_mfma_kernel<32><<<mb32_8, 256, 0, stream>>>(aggh, WT[li][0], W[li][1], h1h,
                                                       N, Din, Dout, mb32, 0, 1, nullptr);
      gemm_mfma_kernel<32><<<mb32_8, 256, 0, stream>>>(h1h, WT[li][1], W[li][3], h2h,
                                                       N, Dout, Dout, mb32, 0, 0, stats);
    } else {
      int cbShift = (Dout == 256) ? 1 : 2;
      int nblocks = mb64_8 << cbShift;
      gemm_mfma_kernel<64><<<nblocks, 256, 0, stream>>>(aggh, WT[li][0], W[li][1], h1h,
                                                        N, Din, Dout, mb64, cbShift, 1, nullptr);
      gemm_mfma_kernel<64><<<nblocks, 256, 0, stream>>>(h1h, WT[li][1], W[li][3], h2h,
                                                        N, Dout, Dout, mb64, cbShift, 0, stats);
    }
    bn_prep_kernel<<<(Dout + 255) / 256, 256, 0, stream>>>(stats, W[li][4], W[li][5], Dout, 1.0f / N);
    if (li == 2) {
      bn_pool_kernel<<<64 * 8, 256, 0, stream>>>(h2h, stats, batch, pooled, N);
    }
  }
  out_kernel<<<64, 64, 0, stream>>>(pooled, wo, bo, out);
}